// Round 1
// baseline (3334.723 us; speedup 1.0000x reference)
//
#include <hip/hip_runtime.h>
#include <math.h>

#define NB 8
#define NC 128
#define NT 4096
#define NF 2049
#define ROWS 4

// ---------------------------------------------------------------------------
// In-place radix-2 DIT FFT, length 4096, data pre-loaded in bit-reversed order.
// Forward transform (exp(-i...)), unnormalized. 256 threads.
// ---------------------------------------------------------------------------
__device__ __forceinline__ void fft4096(float2* buf) {
    for (int half = 1; half < NT; half <<= 1) {
        __syncthreads();
        const float fac = -(float)M_PI / (float)half;
        for (int t = threadIdx.x; t < NT / 2; t += 256) {
            int pos = t & (half - 1);
            int i = 2 * t - pos;
            int j = i + half;
            float sw, cw;
            __sincosf(fac * (float)pos, &sw, &cw);
            float2 u = buf[i], v = buf[j];
            float vr = v.x * cw - v.y * sw;
            float vi = v.x * sw + v.y * cw;
            buf[i] = make_float2(u.x + vr, u.y + vi);
            buf[j] = make_float2(u.x - vr, u.y - vi);
        }
    }
    __syncthreads();
}

// rfft of x_in[b,c,:] (ortho) -> Xf interleaved (B, F, 2C): [re,im] per channel
__global__ __launch_bounds__(256) void fft_fwd_kernel(const float* __restrict__ x_in,
                                                      float* __restrict__ Xf) {
    __shared__ float2 buf[NT];
    int bc = blockIdx.x, b = bc >> 7, c = bc & 127;
    const float* xrow = x_in + (size_t)bc * NT;
    for (int i = threadIdx.x; i < NT; i += 256) {
        int r = __brev((unsigned)i) >> 20;  // 12-bit reversal
        buf[r] = make_float2(xrow[i], 0.0f);
    }
    fft4096(buf);
    const float inv = 1.0f / 64.0f;  // 1/sqrt(4096)
    for (int f = threadIdx.x; f < NF; f += 256) {
        float2 v = buf[f];
        size_t o = ((size_t)b * NF + f) * (2 * NC) + 2 * c;
        Xf[o] = v.x * inv;
        Xf[o + 1] = v.y * inv;
    }
}

// K = X @ W_K^T (+ 64*b_K at f=0), V likewise. One block per (b,f), 128 threads.
__global__ __launch_bounds__(128) void kv_kernel(const float* __restrict__ Xf,
                                                 const float* __restrict__ W_K,
                                                 const float* __restrict__ b_K,
                                                 const float* __restrict__ W_V,
                                                 const float* __restrict__ b_V,
                                                 float* __restrict__ Kf,
                                                 float* __restrict__ Vf) {
    int bf = blockIdx.x;
    __shared__ float xr[2 * NC];
    const float* xrow = Xf + (size_t)bf * 2 * NC;
    for (int i = threadIdx.x; i < 2 * NC; i += 128) xr[i] = xrow[i];
    __syncthreads();
    int j = threadIdx.x;
    const float* wk = W_K + j * NC;
    const float* wv = W_V + j * NC;
    float kr = 0.f, ki = 0.f, vr = 0.f, vi = 0.f;
    for (int c = 0; c < NC; ++c) {
        float w1 = wk[c], w2 = wv[c];
        float xre = xr[2 * c], xim = xr[2 * c + 1];
        kr += w1 * xre; ki += w1 * xim;
        vr += w2 * xre; vi += w2 * xim;
    }
    if (bf % NF == 0) {  // f == 0: bias contributes sqrt(N)*b at DC only
        kr += 64.0f * b_K[j];
        vr += 64.0f * b_V[j];
    }
    size_t o = (size_t)bf * 2 * NC + 2 * j;
    Kf[o] = kr; Kf[o + 1] = ki;
    Vf[o] = vr; Vf[o + 1] = vi;
}

// energy[b,f] = sum_c |X|^2
__global__ __launch_bounds__(256) void energy_kernel(const float* __restrict__ Xf,
                                                     float* __restrict__ energy) {
    int idx = blockIdx.x * 256 + threadIdx.x;
    if (idx >= NB * NF) return;
    const float4* row = (const float4*)(Xf + (size_t)idx * 2 * NC);
    float e = 0.f;
    for (int i = 0; i < 64; ++i) {
        float4 v = row[i];
        e += v.x * v.x + v.y * v.y + v.z * v.z + v.w * v.w;
    }
    energy[idx] = e;
}

// per-batch median (odd n=2049 -> sorted[1024]) via O(n^2) stable rank selection
__global__ __launch_bounds__(256) void median_kernel(const float* __restrict__ energy,
                                                     float* __restrict__ med) {
    int b = blockIdx.x;
    __shared__ float e[NF];
    for (int i = threadIdx.x; i < NF; i += 256) e[i] = energy[b * NF + i];
    __syncthreads();
    for (int i = threadIdx.x; i < NF; i += 256) {
        float ei = e[i];
        int rank = 0;
        for (int j = 0; j < NF; ++j) {
            float ej = e[j];
            rank += (ej < ei) || (ej == ei && j < i);
        }
        if (rank == 1024) med[b] = ei;
    }
}

__global__ __launch_bounds__(256) void norm_kernel(const float* __restrict__ energy,
                                                   const float* __restrict__ med,
                                                   float* __restrict__ nrm) {
    int idx = blockIdx.x * 256 + threadIdx.x;
    if (idx >= NB * NF) return;
    int b = idx / NF;
    nrm[idx] = energy[idx] / (med[b] + 1e-6f);
}

// global order statistics for quantile: stable ranks are unique, so exactly one
// thread matches each target rank. Chunks staged through LDS.
__global__ __launch_bounds__(256) void select_kernel(const float* __restrict__ nrm,
                                                     const float* __restrict__ q,
                                                     float* __restrict__ vk) {
    const int n = NB * NF;
    int i = blockIdx.x * 256 + threadIdx.x;
    float ei = (i < n) ? nrm[i] : 0.f;
    int rank = 0;
    __shared__ float chunk[4096];
    for (int base = 0; base < n; base += 4096) {
        int cnt = min(4096, n - base);
        __syncthreads();
        for (int t = threadIdx.x; t < cnt; t += 256) chunk[t] = nrm[base + t];
        __syncthreads();
        if (i < n) {
            for (int t = 0; t < cnt; ++t) {
                float ej = chunk[t];
                int j = base + t;
                rank += (ej < ei) || (ej == ei && j < i);
            }
        }
    }
    if (i < n) {
        double pos = (double)q[0] * (double)(n - 1);
        int k0 = (int)floor(pos);
        int k1 = min(k0 + 1, n - 1);
        if (rank == k0) vk[0] = ei;
        if (rank == k1) vk[1] = ei;
    }
}

__global__ void thresh_kernel(const float* __restrict__ vk,
                              const float* __restrict__ q,
                              float* __restrict__ thr) {
    if (threadIdx.x == 0 && blockIdx.x == 0) {
        const int n = NB * NF;
        double pos = (double)q[0] * (double)(n - 1);
        double k0 = floor(pos);
        double frac = pos - k0;
        thr[0] = (float)((double)vk[0] + ((double)vk[1] - (double)vk[0]) * frac);
    }
}

// Attention: 4 rows per block, scores for all g in LDS, two-pass softmax.
// score(f,g) = |sum_c X[f,c]*K[g,c]| * C^-0.5 ; ctx(f,:) = softmax row . V
__global__ __launch_bounds__(256) void attn_kernel(const float* __restrict__ Xf,
                                                   const float* __restrict__ Kf,
                                                   const float* __restrict__ Vf,
                                                   float* __restrict__ Ctx) {
    const float SCALE = 0.08838834764831845f;  // 1/sqrt(128)
    int tile = blockIdx.x;
    int b = tile / 513;
    int f0 = (tile % 513) * ROWS;
    __shared__ __align__(16) float xr[ROWS][2 * NC];
    __shared__ float sc[ROWS][NF];
    __shared__ float red[256];
    __shared__ float l_s[ROWS];

    for (int i = threadIdx.x; i < ROWS * 2 * NC; i += 256) {
        int r = i / (2 * NC), k = i % (2 * NC);
        int f = f0 + r;
        xr[r][k] = (f < NF) ? Xf[((size_t)b * NF + f) * 2 * NC + k] : 0.f;
    }
    __syncthreads();

    // pass 1: scores
    for (int g = threadIdx.x; g < NF; g += 256) {
        const float4* krow = (const float4*)(Kf + ((size_t)b * NF + g) * 2 * NC);
        float re[ROWS] = {0, 0, 0, 0}, im[ROWS] = {0, 0, 0, 0};
        for (int jj = 0; jj < 64; ++jj) {
            float4 k4 = krow[jj];
#pragma unroll
            for (int r = 0; r < ROWS; ++r) {
                float4 x4 = ((const float4*)xr[r])[jj];
                re[r] += x4.x * k4.x - x4.y * k4.y + x4.z * k4.z - x4.w * k4.w;
                im[r] += x4.x * k4.y + x4.y * k4.x + x4.z * k4.w + x4.w * k4.z;
            }
        }
#pragma unroll
        for (int r = 0; r < ROWS; ++r)
            sc[r][g] = sqrtf(re[r] * re[r] + im[r] * im[r]) * SCALE;
    }
    __syncthreads();

    // softmax per row
    for (int r = 0; r < ROWS; ++r) {
        float mx = -1e30f;
        for (int g = threadIdx.x; g < NF; g += 256) mx = fmaxf(mx, sc[r][g]);
        red[threadIdx.x] = mx;
        __syncthreads();
        for (int s = 128; s > 0; s >>= 1) {
            if (threadIdx.x < s) red[threadIdx.x] = fmaxf(red[threadIdx.x], red[threadIdx.x + s]);
            __syncthreads();
        }
        float m = red[0];
        __syncthreads();
        float sum = 0.f;
        for (int g = threadIdx.x; g < NF; g += 256) {
            float p = __expf(sc[r][g] - m);
            sc[r][g] = p;
            sum += p;
        }
        red[threadIdx.x] = sum;
        __syncthreads();
        for (int s = 128; s > 0; s >>= 1) {
            if (threadIdx.x < s) red[threadIdx.x] += red[threadIdx.x + s];
            __syncthreads();
        }
        if (threadIdx.x == 0) l_s[r] = red[0];
        __syncthreads();
    }

    // pass 2: ctx[f, j] = sum_g p[f,g] * V[g, j], j = interleaved float index
    int j = threadIdx.x;
    float acc[ROWS] = {0, 0, 0, 0};
    const float* vbase = Vf + (size_t)b * NF * 2 * NC + j;
    for (int g = 0; g < NF; ++g) {
        float v = vbase[(size_t)g * 2 * NC];
#pragma unroll
        for (int r = 0; r < ROWS; ++r) acc[r] += sc[r][g] * v;
    }
#pragma unroll
    for (int r = 0; r < ROWS; ++r) {
        int f = f0 + r;
        if (f < NF) Ctx[((size_t)b * NF + f) * 2 * NC + j] = acc[r] / l_s[r];
    }
}

// ctx += mask * X * (w_high[:,0] + i w_high[:,1])
__global__ __launch_bounds__(256) void hifreq_kernel(float* __restrict__ Ctx,
                                                     const float* __restrict__ Xf,
                                                     const float* __restrict__ nrm,
                                                     const float* __restrict__ thr,
                                                     const float* __restrict__ w_high) {
    int idx = blockIdx.x * 256 + threadIdx.x;
    if (idx >= NB * NF * NC) return;
    int c = idx & 127;
    int bf = idx >> 7;
    if (nrm[bf] > thr[0]) {
        float wr = w_high[2 * c], wi = w_high[2 * c + 1];
        size_t o = (size_t)bf * 2 * NC + 2 * c;
        float xre = Xf[o], xim = Xf[o + 1];
        Ctx[o] += xre * wr - xim * wi;
        Ctx[o + 1] += xre * wi + xim * wr;
    }
}

// irfft (ortho) via conj trick: out[n] = Re(FFT(conj(Yfull))[n]) / sqrt(N)
__global__ __launch_bounds__(256) void fft_inv_kernel(const float* __restrict__ Ctx,
                                                      float* __restrict__ out) {
    __shared__ float2 buf[NT];
    int bc = blockIdx.x, b = bc >> 7, c = bc & 127;
    const float* base = Ctx + (size_t)b * NF * 2 * NC + 2 * c;
    for (int f = threadIdx.x; f < NT; f += 256) {
        float re, im;
        if (f <= NT / 2) {
            re = base[(size_t)f * 2 * NC];
            im = -base[(size_t)f * 2 * NC + 1];
        } else {
            int g = NT - f;  // conj(Y[g]) conj'd again = original
            re = base[(size_t)g * 2 * NC];
            im = base[(size_t)g * 2 * NC + 1];
        }
        int r = __brev((unsigned)f) >> 20;
        buf[r] = make_float2(re, im);
    }
    fft4096(buf);
    float* orow = out + (size_t)bc * NT;
    const float inv = 1.0f / 64.0f;
    for (int n = threadIdx.x; n < NT; n += 256) orow[n] = buf[n].x * inv;
}

extern "C" void kernel_launch(void* const* d_in, const int* in_sizes, int n_in,
                              void* d_out, int out_size, void* d_ws, size_t ws_size,
                              hipStream_t stream) {
    const float* x_in   = (const float*)d_in[0];
    const float* W_K    = (const float*)d_in[1];
    const float* b_K    = (const float*)d_in[2];
    const float* W_V    = (const float*)d_in[3];
    const float* b_V    = (const float*)d_in[4];
    const float* w_high = (const float*)d_in[5];
    const float* qpar   = (const float*)d_in[6];
    float* out = (float*)d_out;

    float* ws = (float*)d_ws;
    const size_t SPEC = (size_t)NB * NF * 2 * NC;  // 4,196,352 floats
    float* Xf     = ws;
    float* Kf     = Xf + SPEC;
    float* Vf     = Kf + SPEC;
    float* Ctx    = Vf + SPEC;
    float* energy = Ctx + SPEC;          // NB*NF
    float* med    = energy + NB * NF;    // 8
    float* nrm    = med + 8;             // NB*NF
    float* vk     = nrm + NB * NF;       // 2 (+pad)
    float* thr    = vk + 4;              // 1
    // total ~67.3 MB of ws

    fft_fwd_kernel<<<NB * NC, 256, 0, stream>>>(x_in, Xf);
    kv_kernel<<<NB * NF, 128, 0, stream>>>(Xf, W_K, b_K, W_V, b_V, Kf, Vf);
    energy_kernel<<<(NB * NF + 255) / 256, 256, 0, stream>>>(Xf, energy);
    median_kernel<<<NB, 256, 0, stream>>>(energy, med);
    norm_kernel<<<(NB * NF + 255) / 256, 256, 0, stream>>>(energy, med, nrm);
    select_kernel<<<(NB * NF + 255) / 256, 256, 0, stream>>>(nrm, qpar, vk);
    thresh_kernel<<<1, 64, 0, stream>>>(vk, qpar, thr);
    attn_kernel<<<NB * 513, 256, 0, stream>>>(Xf, Kf, Vf, Ctx);
    hifreq_kernel<<<(NB * NF * NC + 255) / 256, 256, 0, stream>>>(Ctx, Xf, nrm, thr, w_high);
    fft_inv_kernel<<<NB * NC, 256, 0, stream>>>(Ctx, out);
}

// Round 2
// 1564.932 us; speedup vs baseline: 2.1309x; 2.1309x over previous
//
#include <hip/hip_runtime.h>
#include <math.h>

#define NB 8
#define NC 128
#define NT 4096
#define NF 2049
#define FP 2176   // padded F = 17*128
#define LDP 72    // LDS row pitch (64 + 8 bf16) -> 144 B, conflict-free phases

typedef __bf16 bf16;
typedef __bf16 bf16x8 __attribute__((ext_vector_type(8)));
typedef float f32x4 __attribute__((ext_vector_type(4)));

// ---------------------------------------------------------------------------
// In-place radix-2 DIT FFT, length 4096, bit-reversed input. 256 threads.
// ---------------------------------------------------------------------------
__device__ __forceinline__ void fft4096(float2* buf) {
    for (int half = 1; half < NT; half <<= 1) {
        __syncthreads();
        const float fac = -(float)M_PI / (float)half;
        for (int t = threadIdx.x; t < NT / 2; t += 256) {
            int pos = t & (half - 1);
            int i = 2 * t - pos;
            int j = i + half;
            float sw, cw;
            __sincosf(fac * (float)pos, &sw, &cw);
            float2 u = buf[i], v = buf[j];
            float vr = v.x * cw - v.y * sw;
            float vi = v.x * sw + v.y * cw;
            buf[i] = make_float2(u.x + vr, u.y + vi);
            buf[j] = make_float2(u.x - vr, u.y - vi);
        }
    }
    __syncthreads();
}

__global__ __launch_bounds__(256) void fft_fwd_kernel(const float* __restrict__ x_in,
                                                      float* __restrict__ Xf) {
    __shared__ float2 buf[NT];
    int bc = blockIdx.x, b = bc >> 7, c = bc & 127;
    const float* xrow = x_in + (size_t)bc * NT;
    for (int i = threadIdx.x; i < NT; i += 256) {
        int r = __brev((unsigned)i) >> 20;
        buf[r] = make_float2(xrow[i], 0.0f);
    }
    fft4096(buf);
    const float inv = 1.0f / 64.0f;
    for (int f = threadIdx.x; f < NF; f += 256) {
        float2 v = buf[f];
        size_t o = ((size_t)b * NF + f) * (2 * NC) + 2 * c;
        Xf[o] = v.x * inv;
        Xf[o + 1] = v.y * inv;
    }
}

// Xf fp32 (B,NF,256) -> Xb bf16 (B,FP,256), pad rows zero
__global__ __launch_bounds__(256) void xpack_kernel(const float* __restrict__ Xf,
                                                    bf16* __restrict__ Xb) {
    int idx = blockIdx.x * 256 + threadIdx.x;
    if (idx >= NB * FP * 256) return;
    int k = idx & 255;
    int fp = (idx >> 8) % FP;
    int b = idx / (FP * 256);
    float v = (fp < NF) ? Xf[((size_t)b * NF + fp) * 256 + k] : 0.f;
    Xb[idx] = (bf16)v;
}

// K,V rows; writes packed bf16:
//  K1[g, 2c]=Kr, [2c+1]=-Ki ; K2[g,2c]=Ki, [2c+1]=Kr ; Vt[j, g] (transposed)
__global__ __launch_bounds__(128) void kvpack_kernel(const float* __restrict__ Xf,
                                                     const float* __restrict__ W_K,
                                                     const float* __restrict__ b_K,
                                                     const float* __restrict__ W_V,
                                                     const float* __restrict__ b_V,
                                                     bf16* __restrict__ K1,
                                                     bf16* __restrict__ K2,
                                                     bf16* __restrict__ Vt) {
    __shared__ float xr[2 * NC];
    int bg = blockIdx.x;
    int b = bg / FP, g = bg % FP;
    int j = threadIdx.x;
    float kr = 0.f, ki = 0.f, vr = 0.f, vi = 0.f;
    if (g < NF) {
        const float* xrow = Xf + ((size_t)b * NF + g) * 2 * NC;
        for (int i = j; i < 2 * NC; i += 128) xr[i] = xrow[i];
        __syncthreads();
        const float* wk = W_K + j * NC;
        const float* wv = W_V + j * NC;
        for (int c = 0; c < NC; ++c) {
            float w1 = wk[c], w2 = wv[c];
            float xre = xr[2 * c], xim = xr[2 * c + 1];
            kr += w1 * xre; ki += w1 * xim;
            vr += w2 * xre; vi += w2 * xim;
        }
        if (g == 0) { kr += 64.0f * b_K[j]; vr += 64.0f * b_V[j]; }
    }
    size_t o = (size_t)bg * 2 * NC;
    K1[o + 2 * j] = (bf16)kr;  K1[o + 2 * j + 1] = (bf16)(-ki);
    K2[o + 2 * j] = (bf16)ki;  K2[o + 2 * j + 1] = (bf16)kr;
    Vt[((size_t)b * 256 + 2 * j) * FP + g] = (bf16)vr;
    Vt[((size_t)b * 256 + 2 * j + 1) * FP + g] = (bf16)vi;
}

__global__ __launch_bounds__(256) void energy_kernel(const float* __restrict__ Xf,
                                                     float* __restrict__ energy) {
    int idx = blockIdx.x * 256 + threadIdx.x;
    if (idx >= NB * NF) return;
    const float4* row = (const float4*)(Xf + (size_t)idx * 2 * NC);
    float e = 0.f;
    for (int i = 0; i < 64; ++i) {
        float4 v = row[i];
        e += v.x * v.x + v.y * v.y + v.z * v.z + v.w * v.w;
    }
    energy[idx] = e;
}

__global__ __launch_bounds__(256) void median_kernel(const float* __restrict__ energy,
                                                     float* __restrict__ med) {
    int b = blockIdx.x;
    __shared__ float e[NF];
    for (int i = threadIdx.x; i < NF; i += 256) e[i] = energy[b * NF + i];
    __syncthreads();
    for (int i = threadIdx.x; i < NF; i += 256) {
        float ei = e[i];
        int rank = 0;
        for (int j = 0; j < NF; ++j) {
            float ej = e[j];
            rank += (ej < ei) || (ej == ei && j < i);
        }
        if (rank == 1024) med[b] = ei;
    }
}

__global__ __launch_bounds__(256) void norm_kernel(const float* __restrict__ energy,
                                                   const float* __restrict__ med,
                                                   float* __restrict__ nrm) {
    int idx = blockIdx.x * 256 + threadIdx.x;
    if (idx >= NB * NF) return;
    int b = idx / NF;
    nrm[idx] = energy[idx] / (med[b] + 1e-6f);
}

__global__ __launch_bounds__(256) void select_kernel(const float* __restrict__ nrm,
                                                     const float* __restrict__ q,
                                                     float* __restrict__ vk) {
    const int n = NB * NF;
    int i = blockIdx.x * 256 + threadIdx.x;
    float ei = (i < n) ? nrm[i] : 0.f;
    int rank = 0;
    __shared__ float chunk[4096];
    for (int base = 0; base < n; base += 4096) {
        int cnt = min(4096, n - base);
        __syncthreads();
        for (int t = threadIdx.x; t < cnt; t += 256) chunk[t] = nrm[base + t];
        __syncthreads();
        if (i < n) {
            for (int t = 0; t < cnt; ++t) {
                float ej = chunk[t];
                int j = base + t;
                rank += (ej < ei) || (ej == ei && j < i);
            }
        }
    }
    if (i < n) {
        double pos = (double)q[0] * (double)(n - 1);
        int k0 = (int)floor(pos);
        int k1 = min(k0 + 1, n - 1);
        if (rank == k0) vk[0] = ei;
        if (rank == k1) vk[1] = ei;
    }
}

__global__ void thresh_kernel(const float* __restrict__ vk,
                              const float* __restrict__ q,
                              float* __restrict__ thr) {
    if (threadIdx.x == 0 && blockIdx.x == 0) {
        const int n = NB * NF;
        double pos = (double)q[0] * (double)(n - 1);
        double k0 = floor(pos);
        double frac = pos - k0;
        thr[0] = (float)((double)vk[0] + ((double)vk[1] - (double)vk[0]) * frac);
    }
}

// ---------------------------------------------------------------------------
// Scores via MFMA: S[f,g] = |X[f,:].K[g,:]| * C^-0.5, as two K=256 real GEMMs.
// Block = 128x128 tile, 4 waves, each wave 64x64 (4x4 MFMA tiles), BK=64.
// ---------------------------------------------------------------------------
__global__ __launch_bounds__(256, 2) void score_kernel(const bf16* __restrict__ Xb,
                                                       const bf16* __restrict__ K1,
                                                       const bf16* __restrict__ K2,
                                                       bf16* __restrict__ S) {
    __shared__ bf16 As[128][LDP];
    __shared__ bf16 B1s[128][LDP];
    __shared__ bf16 B2s[128][LDP];
    int blk = blockIdx.x;
    int b = blk / (17 * 17);
    int t2 = blk % (17 * 17);
    int f0 = (t2 / 17) * 128;
    int g0 = (t2 % 17) * 128;
    int tid = threadIdx.x;
    int wave = tid >> 6, lane = tid & 63;
    int m = lane & 15, quad = lane >> 4;
    int row_off = (wave & 1) * 64, col_off = (wave >> 1) * 64;

    f32x4 accRe[4][4] = {};
    f32x4 accIm[4][4] = {};
    const bf16* Abase = Xb + ((size_t)b * FP + f0) * 256;
    const bf16* B1base = K1 + ((size_t)b * FP + g0) * 256;
    const bf16* B2base = K2 + ((size_t)b * FP + g0) * 256;
    int r0 = tid >> 3, c0 = (tid & 7) * 8;

    for (int kk = 0; kk < 256; kk += 64) {
        __syncthreads();
#pragma unroll
        for (int s = 0; s < 4; ++s) {
            int r = r0 + 32 * s;
            *(bf16x8*)&As[r][c0] = *(const bf16x8*)&Abase[(size_t)r * 256 + kk + c0];
            *(bf16x8*)&B1s[r][c0] = *(const bf16x8*)&B1base[(size_t)r * 256 + kk + c0];
            *(bf16x8*)&B2s[r][c0] = *(const bf16x8*)&B2base[(size_t)r * 256 + kk + c0];
        }
        __syncthreads();
#pragma unroll
        for (int k2 = 0; k2 < 64; k2 += 32) {
            bf16x8 a[4], b1[4], b2[4];
            int kq = k2 + quad * 8;
#pragma unroll
            for (int i = 0; i < 4; ++i) a[i] = *(const bf16x8*)&As[row_off + i * 16 + m][kq];
#pragma unroll
            for (int j = 0; j < 4; ++j) b1[j] = *(const bf16x8*)&B1s[col_off + j * 16 + m][kq];
#pragma unroll
            for (int j = 0; j < 4; ++j) b2[j] = *(const bf16x8*)&B2s[col_off + j * 16 + m][kq];
#pragma unroll
            for (int i = 0; i < 4; ++i)
#pragma unroll
                for (int j = 0; j < 4; ++j) {
                    accRe[i][j] = __builtin_amdgcn_mfma_f32_16x16x32_bf16(a[i], b1[j], accRe[i][j], 0, 0, 0);
                    accIm[i][j] = __builtin_amdgcn_mfma_f32_16x16x32_bf16(a[i], b2[j], accIm[i][j], 0, 0, 0);
                }
        }
    }
    const float SCALE = 0.08838834764831845f;  // 1/sqrt(128)
    bf16* Sb = S + (size_t)b * FP * FP;
#pragma unroll
    for (int i = 0; i < 4; ++i)
#pragma unroll
        for (int j = 0; j < 4; ++j)
#pragma unroll
            for (int r = 0; r < 4; ++r) {
                int row = f0 + row_off + i * 16 + quad * 4 + r;
                int col = g0 + col_off + j * 16 + m;
                float re = accRe[i][j][r], im = accIm[i][j][r];
                Sb[(size_t)row * FP + col] = (bf16)(sqrtf(re * re + im * im) * SCALE);
            }
}

// row softmax in place (bf16), zero pad cols
__global__ __launch_bounds__(256) void softmax_kernel(bf16* __restrict__ S) {
    int bf = blockIdx.x;
    int b = bf / NF, f = bf % NF;
    bf16* row = S + ((size_t)b * FP + f) * FP;
    __shared__ float red[256];
    float mx = -1e30f;
    for (int g = threadIdx.x; g < NF; g += 256) mx = fmaxf(mx, (float)row[g]);
    red[threadIdx.x] = mx;
    __syncthreads();
    for (int s = 128; s > 0; s >>= 1) {
        if (threadIdx.x < s) red[threadIdx.x] = fmaxf(red[threadIdx.x], red[threadIdx.x + s]);
        __syncthreads();
    }
    float mval = red[0];
    __syncthreads();
    float sum = 0.f;
    for (int g = threadIdx.x; g < NF; g += 256) sum += __expf((float)row[g] - mval);
    red[threadIdx.x] = sum;
    __syncthreads();
    for (int s = 128; s > 0; s >>= 1) {
        if (threadIdx.x < s) red[threadIdx.x] += red[threadIdx.x + s];
        __syncthreads();
    }
    float inv = 1.f / red[0];
    for (int g = threadIdx.x; g < FP; g += 256) {
        float p = (g < NF) ? __expf((float)row[g] - mval) * inv : 0.f;
        row[g] = (bf16)p;
    }
}

// ---------------------------------------------------------------------------
// Context via MFMA: Ctx[f,j] = sum_g P[f,g] Vt[j,g].  Block = 64 rows x 256
// cols, 4 waves (each 64x64), K = 2176 in BK=64 steps.
// ---------------------------------------------------------------------------
__global__ __launch_bounds__(256, 2) void context_kernel(const bf16* __restrict__ P,
                                                         const bf16* __restrict__ Vt,
                                                         float* __restrict__ Ctx) {
    __shared__ bf16 Ps[64][LDP];
    __shared__ bf16 Vs[256][LDP];
    int blk = blockIdx.x;
    int b = blk / 33;
    int f0 = (blk % 33) * 64;
    int tid = threadIdx.x;
    int wave = tid >> 6, lane = tid & 63;
    int m = lane & 15, quad = lane >> 4;
    int col_off = wave * 64;

    f32x4 acc[4][4] = {};
    const bf16* Pbase = P + ((size_t)b * FP + f0) * FP;
    const bf16* Vbase = Vt + (size_t)b * 256 * FP;
    int r0 = tid >> 3, c0 = (tid & 7) * 8;

    for (int kk = 0; kk < FP; kk += 64) {
        __syncthreads();
#pragma unroll
        for (int s = 0; s < 2; ++s) {
            int r = r0 + 32 * s;
            *(bf16x8*)&Ps[r][c0] = *(const bf16x8*)&Pbase[(size_t)r * FP + kk + c0];
        }
#pragma unroll
        for (int s = 0; s < 8; ++s) {
            int r = r0 + 32 * s;
            *(bf16x8*)&Vs[r][c0] = *(const bf16x8*)&Vbase[(size_t)r * FP + kk + c0];
        }
        __syncthreads();
#pragma unroll
        for (int k2 = 0; k2 < 64; k2 += 32) {
            bf16x8 a[4], bb[4];
            int kq = k2 + quad * 8;
#pragma unroll
            for (int i = 0; i < 4; ++i) a[i] = *(const bf16x8*)&Ps[i * 16 + m][kq];
#pragma unroll
            for (int j = 0; j < 4; ++j) bb[j] = *(const bf16x8*)&Vs[col_off + j * 16 + m][kq];
#pragma unroll
            for (int i = 0; i < 4; ++i)
#pragma unroll
                for (int j = 0; j < 4; ++j)
                    acc[i][j] = __builtin_amdgcn_mfma_f32_16x16x32_bf16(a[i], bb[j], acc[i][j], 0, 0, 0);
        }
    }
#pragma unroll
    for (int i = 0; i < 4; ++i)
#pragma unroll
        for (int j = 0; j < 4; ++j)
#pragma unroll
            for (int r = 0; r < 4; ++r) {
                int row = f0 + i * 16 + quad * 4 + r;
                int col = col_off + j * 16 + m;
                if (row < NF) Ctx[((size_t)b * NF + row) * 256 + col] = acc[i][j][r];
            }
}

// ctx += mask * X * (w_high[:,0] + i w_high[:,1])
__global__ __launch_bounds__(256) void hifreq_kernel(float* __restrict__ Ctx,
                                                     const float* __restrict__ Xf,
                                                     const float* __restrict__ nrm,
                                                     const float* __restrict__ thr,
                                                     const float* __restrict__ w_high) {
    int idx = blockIdx.x * 256 + threadIdx.x;
    if (idx >= NB * NF * NC) return;
    int c = idx & 127;
    int bf = idx >> 7;
    if (nrm[bf] > thr[0]) {
        float wr = w_high[2 * c], wi = w_high[2 * c + 1];
        size_t o = (size_t)bf * 2 * NC + 2 * c;
        float xre = Xf[o], xim = Xf[o + 1];
        Ctx[o] += xre * wr - xim * wi;
        Ctx[o + 1] += xre * wi + xim * wr;
    }
}

__global__ __launch_bounds__(256) void fft_inv_kernel(const float* __restrict__ Ctx,
                                                      float* __restrict__ out) {
    __shared__ float2 buf[NT];
    int bc = blockIdx.x, b = bc >> 7, c = bc & 127;
    const float* base = Ctx + (size_t)b * NF * 2 * NC + 2 * c;
    for (int f = threadIdx.x; f < NT; f += 256) {
        float re, im;
        if (f <= NT / 2) {
            re = base[(size_t)f * 2 * NC];
            im = -base[(size_t)f * 2 * NC + 1];
        } else {
            int g = NT - f;
            re = base[(size_t)g * 2 * NC];
            im = base[(size_t)g * 2 * NC + 1];
        }
        int r = __brev((unsigned)f) >> 20;
        buf[r] = make_float2(re, im);
    }
    fft4096(buf);
    float* orow = out + (size_t)bc * NT;
    const float inv = 1.0f / 64.0f;
    for (int n = threadIdx.x; n < NT; n += 256) orow[n] = buf[n].x * inv;
}

extern "C" void kernel_launch(void* const* d_in, const int* in_sizes, int n_in,
                              void* d_out, int out_size, void* d_ws, size_t ws_size,
                              hipStream_t stream) {
    const float* x_in = (const float*)d_in[0];
    const float* W_K = (const float*)d_in[1];
    const float* b_K = (const float*)d_in[2];
    const float* W_V = (const float*)d_in[3];
    const float* b_V = (const float*)d_in[4];
    const float* w_high = (const float*)d_in[5];
    const float* qpar = (const float*)d_in[6];
    float* out = (float*)d_out;

    char* w = (char*)d_ws;
    const size_t SPECB = (size_t)NB * NF * 256 * 4;       // 16.8 MB
    float* Xf = (float*)w;            w += SPECB;
    float* Ctx = (float*)w;           w += SPECB;
    float* energy = (float*)w;        w += (size_t)NB * NF * 4;
    float* med = (float*)w;           w += 64;
    float* nrm = (float*)w;           w += (size_t)NB * NF * 4;
    float* vk = (float*)w;            w += 64;
    float* thr = (float*)w;           w += 64;
    w = (char*)(((uintptr_t)w + 255) & ~(uintptr_t)255);
    bf16* S = (bf16*)w;               w += (size_t)NB * FP * FP * 2;    // 75.8 MB
    bf16* Xb = (bf16*)w;              w += (size_t)NB * FP * 256 * 2;   // 8.9 MB
    bf16* K1 = (bf16*)w;              w += (size_t)NB * FP * 256 * 2;
    bf16* K2 = (bf16*)w;              w += (size_t)NB * FP * 256 * 2;
    bf16* Vt = (bf16*)w;              w += (size_t)NB * 256 * FP * 2;
    // total ~145 MB

    fft_fwd_kernel<<<NB * NC, 256, 0, stream>>>(x_in, Xf);
    xpack_kernel<<<(NB * FP * 256 + 255) / 256, 256, 0, stream>>>(Xf, Xb);
    kvpack_kernel<<<NB * FP, 128, 0, stream>>>(Xf, W_K, b_K, W_V, b_V, K1, K2, Vt);
    energy_kernel<<<(NB * NF + 255) / 256, 256, 0, stream>>>(Xf, energy);
    median_kernel<<<NB, 256, 0, stream>>>(energy, med);
    norm_kernel<<<(NB * NF + 255) / 256, 256, 0, stream>>>(energy, med, nrm);
    select_kernel<<<(NB * NF + 255) / 256, 256, 0, stream>>>(nrm, qpar, vk);
    thresh_kernel<<<1, 64, 0, stream>>>(vk, qpar, thr);
    score_kernel<<<NB * 17 * 17, 256, 0, stream>>>(Xb, K1, K2, S);
    softmax_kernel<<<NB * NF, 256, 0, stream>>>(S);
    context_kernel<<<NB * 33, 256, 0, stream>>>(S, Vt, Ctx);
    hifreq_kernel<<<(NB * NF * NC + 255) / 256, 256, 0, stream>>>(Ctx, Xf, nrm, thr, w_high);
    fft_inv_kernel<<<NB * NC, 256, 0, stream>>>(Ctx, out);
}

// Round 3
// 1228.306 us; speedup vs baseline: 2.7149x; 1.2741x over previous
//
#include <hip/hip_runtime.h>
#include <math.h>

#define NB 8
#define NC 128
#define NT 4096
#define NF 2049
#define FP 2176   // padded F = 17*128
#define LDP 72    // LDS row pitch (64 + 8 bf16) -> 144 B, conflict-free phases

typedef __bf16 bf16;
typedef __bf16 bf16x8 __attribute__((ext_vector_type(8)));
typedef float f32x4 __attribute__((ext_vector_type(4)));

// ---------------------------------------------------------------------------
// In-place radix-2 DIT FFT, length 4096, bit-reversed input. 256 threads.
// ---------------------------------------------------------------------------
__device__ __forceinline__ void fft4096(float2* buf) {
    for (int half = 1; half < NT; half <<= 1) {
        __syncthreads();
        const float fac = -(float)M_PI / (float)half;
        for (int t = threadIdx.x; t < NT / 2; t += 256) {
            int pos = t & (half - 1);
            int i = 2 * t - pos;
            int j = i + half;
            float sw, cw;
            __sincosf(fac * (float)pos, &sw, &cw);
            float2 u = buf[i], v = buf[j];
            float vr = v.x * cw - v.y * sw;
            float vi = v.x * sw + v.y * cw;
            buf[i] = make_float2(u.x + vr, u.y + vi);
            buf[j] = make_float2(u.x - vr, u.y - vi);
        }
    }
    __syncthreads();
}

__global__ __launch_bounds__(256) void fft_fwd_kernel(const float* __restrict__ x_in,
                                                      float* __restrict__ Xf) {
    __shared__ float2 buf[NT];
    int bc = blockIdx.x, b = bc >> 7, c = bc & 127;
    const float* xrow = x_in + (size_t)bc * NT;
    for (int i = threadIdx.x; i < NT; i += 256) {
        int r = __brev((unsigned)i) >> 20;
        buf[r] = make_float2(xrow[i], 0.0f);
    }
    fft4096(buf);
    const float inv = 1.0f / 64.0f;
    for (int f = threadIdx.x; f < NF; f += 256) {
        float2 v = buf[f];
        size_t o = ((size_t)b * NF + f) * (2 * NC) + 2 * c;
        Xf[o] = v.x * inv;
        Xf[o + 1] = v.y * inv;
    }
}

// Xf fp32 (B,NF,256) -> Xb bf16 (B,FP,256), pad rows zero
__global__ __launch_bounds__(256) void xpack_kernel(const float* __restrict__ Xf,
                                                    bf16* __restrict__ Xb) {
    int idx = blockIdx.x * 256 + threadIdx.x;
    if (idx >= NB * FP * 256) return;
    int k = idx & 255;
    int fp = (idx >> 8) % FP;
    int b = idx / (FP * 256);
    float v = (fp < NF) ? Xf[((size_t)b * NF + fp) * 256 + k] : 0.f;
    Xb[idx] = (bf16)v;
}

// K,V rows; writes packed bf16:
//  K1[g, 2c]=Kr, [2c+1]=-Ki ; K2[g,2c]=Ki, [2c+1]=Kr ; Vt[j, g] (transposed)
__global__ __launch_bounds__(128) void kvpack_kernel(const float* __restrict__ Xf,
                                                     const float* __restrict__ W_K,
                                                     const float* __restrict__ b_K,
                                                     const float* __restrict__ W_V,
                                                     const float* __restrict__ b_V,
                                                     bf16* __restrict__ K1,
                                                     bf16* __restrict__ K2,
                                                     bf16* __restrict__ Vt) {
    __shared__ float xr[2 * NC];
    int bg = blockIdx.x;
    int b = bg / FP, g = bg % FP;
    int j = threadIdx.x;
    float kr = 0.f, ki = 0.f, vr = 0.f, vi = 0.f;
    if (g < NF) {
        const float* xrow = Xf + ((size_t)b * NF + g) * 2 * NC;
        for (int i = j; i < 2 * NC; i += 128) xr[i] = xrow[i];
        __syncthreads();
        const float* wk = W_K + j * NC;
        const float* wv = W_V + j * NC;
        for (int c = 0; c < NC; ++c) {
            float w1 = wk[c], w2 = wv[c];
            float xre = xr[2 * c], xim = xr[2 * c + 1];
            kr += w1 * xre; ki += w1 * xim;
            vr += w2 * xre; vi += w2 * xim;
        }
        if (g == 0) { kr += 64.0f * b_K[j]; vr += 64.0f * b_V[j]; }
    }
    size_t o = (size_t)bg * 2 * NC;
    K1[o + 2 * j] = (bf16)kr;  K1[o + 2 * j + 1] = (bf16)(-ki);
    K2[o + 2 * j] = (bf16)ki;  K2[o + 2 * j + 1] = (bf16)kr;
    Vt[((size_t)b * 256 + 2 * j) * FP + g] = (bf16)vr;
    Vt[((size_t)b * 256 + 2 * j + 1) * FP + g] = (bf16)vi;
}

__global__ __launch_bounds__(256) void energy_kernel(const float* __restrict__ Xf,
                                                     float* __restrict__ energy) {
    int idx = blockIdx.x * 256 + threadIdx.x;
    if (idx >= NB * NF) return;
    const float4* row = (const float4*)(Xf + (size_t)idx * 2 * NC);
    float e = 0.f;
    for (int i = 0; i < 64; ++i) {
        float4 v = row[i];
        e += v.x * v.x + v.y * v.y + v.z * v.z + v.w * v.w;
    }
    energy[idx] = e;
}

// per-batch median: batch x 9 chunk blocks, float4 LDS rank loop
__global__ __launch_bounds__(256) void median_kernel(const float* __restrict__ energy,
                                                     float* __restrict__ med) {
    int blk = blockIdx.x;
    int b = blk / 9, chunk = blk % 9;
    __shared__ __align__(16) float e[2052];
    for (int i = threadIdx.x; i < 2052; i += 256)
        e[i] = (i < NF) ? energy[b * NF + i] : INFINITY;
    __syncthreads();
    int i = chunk * 256 + threadIdx.x;
    float ei = (i < NF) ? e[i] : 0.f;
    int rank = 0;
#pragma unroll 4
    for (int j4 = 0; j4 < 513; ++j4) {
        float4 v = ((const float4*)e)[j4];
        int j = j4 * 4;
        rank += (v.x < ei) || (v.x == ei && j + 0 < i);
        rank += (v.y < ei) || (v.y == ei && j + 1 < i);
        rank += (v.z < ei) || (v.z == ei && j + 2 < i);
        rank += (v.w < ei) || (v.w == ei && j + 3 < i);
    }
    if (i < NF && rank == 1024) med[b] = ei;
}

__global__ __launch_bounds__(256) void norm_kernel(const float* __restrict__ energy,
                                                   const float* __restrict__ med,
                                                   float* __restrict__ nrm) {
    int idx = blockIdx.x * 256 + threadIdx.x;
    if (idx >= NB * NF) return;
    int b = idx / NF;
    nrm[idx] = energy[idx] / (med[b] + 1e-6f);
}

// global order statistics for quantile, float4 LDS rank loop
__global__ __launch_bounds__(256) void select_kernel(const float* __restrict__ nrm,
                                                     const float* __restrict__ q,
                                                     float* __restrict__ vk) {
    const int n = NB * NF;
    int i = blockIdx.x * 256 + threadIdx.x;
    float ei = (i < n) ? nrm[i] : 0.f;
    int rank = 0;
    __shared__ __align__(16) float chunk[4096];
    for (int base = 0; base < n; base += 4096) {
        int cnt = min(4096, n - base);
        __syncthreads();
        for (int t = threadIdx.x; t < 4096; t += 256)
            chunk[t] = (t < cnt) ? nrm[base + t] : INFINITY;
        __syncthreads();
        if (i < n) {
#pragma unroll 4
            for (int t4 = 0; t4 < 1024; ++t4) {
                float4 v = ((const float4*)chunk)[t4];
                int j = base + t4 * 4;
                rank += (v.x < ei) || (v.x == ei && j + 0 < i);
                rank += (v.y < ei) || (v.y == ei && j + 1 < i);
                rank += (v.z < ei) || (v.z == ei && j + 2 < i);
                rank += (v.w < ei) || (v.w == ei && j + 3 < i);
            }
        }
    }
    if (i < n) {
        double pos = (double)q[0] * (double)(n - 1);
        int k0 = (int)floor(pos);
        int k1 = min(k0 + 1, n - 1);
        if (rank == k0) vk[0] = ei;
        if (rank == k1) vk[1] = ei;
    }
}

__global__ void thresh_kernel(const float* __restrict__ vk,
                              const float* __restrict__ q,
                              float* __restrict__ thr) {
    if (threadIdx.x == 0 && blockIdx.x == 0) {
        const int n = NB * NF;
        double pos = (double)q[0] * (double)(n - 1);
        double k0 = floor(pos);
        double frac = pos - k0;
        thr[0] = (float)((double)vk[0] + ((double)vk[1] - (double)vk[0]) * frac);
    }
}

// ---------------------------------------------------------------------------
// Scores via MFMA: S[f,g] = |X[f,:].K[g,:]| * C^-0.5, as two K=256 real GEMMs.
// ---------------------------------------------------------------------------
__global__ __launch_bounds__(256, 2) void score_kernel(const bf16* __restrict__ Xb,
                                                       const bf16* __restrict__ K1,
                                                       const bf16* __restrict__ K2,
                                                       bf16* __restrict__ S) {
    __shared__ bf16 As[128][LDP];
    __shared__ bf16 B1s[128][LDP];
    __shared__ bf16 B2s[128][LDP];
    int blk = blockIdx.x;
    int b = blk / (17 * 17);
    int t2 = blk % (17 * 17);
    int f0 = (t2 / 17) * 128;
    int g0 = (t2 % 17) * 128;
    int tid = threadIdx.x;
    int wave = tid >> 6, lane = tid & 63;
    int m = lane & 15, quad = lane >> 4;
    int row_off = (wave & 1) * 64, col_off = (wave >> 1) * 64;

    f32x4 accRe[4][4] = {};
    f32x4 accIm[4][4] = {};
    const bf16* Abase = Xb + ((size_t)b * FP + f0) * 256;
    const bf16* B1base = K1 + ((size_t)b * FP + g0) * 256;
    const bf16* B2base = K2 + ((size_t)b * FP + g0) * 256;
    int r0 = tid >> 3, c0 = (tid & 7) * 8;

    for (int kk = 0; kk < 256; kk += 64) {
        __syncthreads();
#pragma unroll
        for (int s = 0; s < 4; ++s) {
            int r = r0 + 32 * s;
            *(bf16x8*)&As[r][c0] = *(const bf16x8*)&Abase[(size_t)r * 256 + kk + c0];
            *(bf16x8*)&B1s[r][c0] = *(const bf16x8*)&B1base[(size_t)r * 256 + kk + c0];
            *(bf16x8*)&B2s[r][c0] = *(const bf16x8*)&B2base[(size_t)r * 256 + kk + c0];
        }
        __syncthreads();
#pragma unroll
        for (int k2 = 0; k2 < 64; k2 += 32) {
            bf16x8 a[4], b1[4], b2[4];
            int kq = k2 + quad * 8;
#pragma unroll
            for (int i = 0; i < 4; ++i) a[i] = *(const bf16x8*)&As[row_off + i * 16 + m][kq];
#pragma unroll
            for (int j = 0; j < 4; ++j) b1[j] = *(const bf16x8*)&B1s[col_off + j * 16 + m][kq];
#pragma unroll
            for (int j = 0; j < 4; ++j) b2[j] = *(const bf16x8*)&B2s[col_off + j * 16 + m][kq];
#pragma unroll
            for (int i = 0; i < 4; ++i)
#pragma unroll
                for (int j = 0; j < 4; ++j) {
                    accRe[i][j] = __builtin_amdgcn_mfma_f32_16x16x32_bf16(a[i], b1[j], accRe[i][j], 0, 0, 0);
                    accIm[i][j] = __builtin_amdgcn_mfma_f32_16x16x32_bf16(a[i], b2[j], accIm[i][j], 0, 0, 0);
                }
        }
    }
    const float SCALE = 0.08838834764831845f;  // 1/sqrt(128)
    bf16* Sb = S + (size_t)b * FP * FP;
#pragma unroll
    for (int i = 0; i < 4; ++i)
#pragma unroll
        for (int j = 0; j < 4; ++j)
#pragma unroll
            for (int r = 0; r < 4; ++r) {
                int row = f0 + row_off + i * 16 + quad * 4 + r;
                int col = g0 + col_off + j * 16 + m;
                float re = accRe[i][j][r], im = accIm[i][j][r];
                Sb[(size_t)row * FP + col] = (bf16)(sqrtf(re * re + im * im) * SCALE);
            }
}

// row softmax in place (bf16), zero pad cols
__global__ __launch_bounds__(256) void softmax_kernel(bf16* __restrict__ S) {
    int bf = blockIdx.x;
    int b = bf / NF, f = bf % NF;
    bf16* row = S + ((size_t)b * FP + f) * FP;
    __shared__ float red[256];
    float mx = -1e30f;
    for (int g = threadIdx.x; g < NF; g += 256) mx = fmaxf(mx, (float)row[g]);
    red[threadIdx.x] = mx;
    __syncthreads();
    for (int s = 128; s > 0; s >>= 1) {
        if (threadIdx.x < s) red[threadIdx.x] = fmaxf(red[threadIdx.x], red[threadIdx.x + s]);
        __syncthreads();
    }
    float mval = red[0];
    __syncthreads();
    float sum = 0.f;
    for (int g = threadIdx.x; g < NF; g += 256) sum += __expf((float)row[g] - mval);
    red[threadIdx.x] = sum;
    __syncthreads();
    for (int s = 128; s > 0; s >>= 1) {
        if (threadIdx.x < s) red[threadIdx.x] += red[threadIdx.x + s];
        __syncthreads();
    }
    float inv = 1.f / red[0];
    for (int g = threadIdx.x; g < FP; g += 256) {
        float p = (g < NF) ? __expf((float)row[g] - mval) * inv : 0.f;
        row[g] = (bf16)p;
    }
}

// ---------------------------------------------------------------------------
// Context via MFMA: Ctx[f,j] = sum_g P[f,g] Vt[j,g].
// ---------------------------------------------------------------------------
__global__ __launch_bounds__(256, 2) void context_kernel(const bf16* __restrict__ P,
                                                         const bf16* __restrict__ Vt,
                                                         float* __restrict__ Ctx) {
    __shared__ bf16 Ps[64][LDP];
    __shared__ bf16 Vs[256][LDP];
    int blk = blockIdx.x;
    int b = blk / 33;
    int f0 = (blk % 33) * 64;
    int tid = threadIdx.x;
    int wave = tid >> 6, lane = tid & 63;
    int m = lane & 15, quad = lane >> 4;
    int col_off = wave * 64;

    f32x4 acc[4][4] = {};
    const bf16* Pbase = P + ((size_t)b * FP + f0) * FP;
    const bf16* Vbase = Vt + (size_t)b * 256 * FP;
    int r0 = tid >> 3, c0 = (tid & 7) * 8;

    for (int kk = 0; kk < FP; kk += 64) {
        __syncthreads();
#pragma unroll
        for (int s = 0; s < 2; ++s) {
            int r = r0 + 32 * s;
            *(bf16x8*)&Ps[r][c0] = *(const bf16x8*)&Pbase[(size_t)r * FP + kk + c0];
        }
#pragma unroll
        for (int s = 0; s < 8; ++s) {
            int r = r0 + 32 * s;
            *(bf16x8*)&Vs[r][c0] = *(const bf16x8*)&Vbase[(size_t)r * FP + kk + c0];
        }
        __syncthreads();
#pragma unroll
        for (int k2 = 0; k2 < 64; k2 += 32) {
            bf16x8 a[4], bb[4];
            int kq = k2 + quad * 8;
#pragma unroll
            for (int i = 0; i < 4; ++i) a[i] = *(const bf16x8*)&Ps[i * 16 + m][kq];
#pragma unroll
            for (int j = 0; j < 4; ++j) bb[j] = *(const bf16x8*)&Vs[col_off + j * 16 + m][kq];
#pragma unroll
            for (int i = 0; i < 4; ++i)
#pragma unroll
                for (int j = 0; j < 4; ++j)
                    acc[i][j] = __builtin_amdgcn_mfma_f32_16x16x32_bf16(a[i], bb[j], acc[i][j], 0, 0, 0);
        }
    }
#pragma unroll
    for (int i = 0; i < 4; ++i)
#pragma unroll
        for (int j = 0; j < 4; ++j)
#pragma unroll
            for (int r = 0; r < 4; ++r) {
                int row = f0 + i * 16 + quad * 4 + r;
                int col = col_off + j * 16 + m;
                if (row < NF) Ctx[((size_t)b * NF + row) * 256 + col] = acc[i][j][r];
            }
}

// ctx += mask * X * (w_high[:,0] + i w_high[:,1])
__global__ __launch_bounds__(256) void hifreq_kernel(float* __restrict__ Ctx,
                                                     const float* __restrict__ Xf,
                                                     const float* __restrict__ nrm,
                                                     const float* __restrict__ thr,
                                                     const float* __restrict__ w_high) {
    int idx = blockIdx.x * 256 + threadIdx.x;
    if (idx >= NB * NF * NC) return;
    int c = idx & 127;
    int bf = idx >> 7;
    if (nrm[bf] > thr[0]) {
        float wr = w_high[2 * c], wi = w_high[2 * c + 1];
        size_t o = (size_t)bf * 2 * NC + 2 * c;
        float xre = Xf[o], xim = Xf[o + 1];
        Ctx[o] += xre * wr - xim * wi;
        Ctx[o + 1] += xre * wi + xim * wr;
    }
}

__global__ __launch_bounds__(256) void fft_inv_kernel(const float* __restrict__ Ctx,
                                                      float* __restrict__ out) {
    __shared__ float2 buf[NT];
    int bc = blockIdx.x, b = bc >> 7, c = bc & 127;
    const float* base = Ctx + (size_t)b * NF * 2 * NC + 2 * c;
    for (int f = threadIdx.x; f < NT; f += 256) {
        float re, im;
        if (f <= NT / 2) {
            re = base[(size_t)f * 2 * NC];
            im = -base[(size_t)f * 2 * NC + 1];
        } else {
            int g = NT - f;
            re = base[(size_t)g * 2 * NC];
            im = base[(size_t)g * 2 * NC + 1];
        }
        int r = __brev((unsigned)f) >> 20;
        buf[r] = make_float2(re, im);
    }
    fft4096(buf);
    float* orow = out + (size_t)bc * NT;
    const float inv = 1.0f / 64.0f;
    for (int n = threadIdx.x; n < NT; n += 256) orow[n] = buf[n].x * inv;
}

extern "C" void kernel_launch(void* const* d_in, const int* in_sizes, int n_in,
                              void* d_out, int out_size, void* d_ws, size_t ws_size,
                              hipStream_t stream) {
    const float* x_in = (const float*)d_in[0];
    const float* W_K = (const float*)d_in[1];
    const float* b_K = (const float*)d_in[2];
    const float* W_V = (const float*)d_in[3];
    const float* b_V = (const float*)d_in[4];
    const float* w_high = (const float*)d_in[5];
    const float* qpar = (const float*)d_in[6];
    float* out = (float*)d_out;

    char* w = (char*)d_ws;
    const size_t SPECB = (size_t)NB * NF * 256 * 4;       // 16.8 MB
    float* Xf = (float*)w;            w += SPECB;
    float* Ctx = (float*)w;           w += SPECB;
    float* energy = (float*)w;        w += (size_t)NB * NF * 4;
    float* med = (float*)w;           w += 64;
    float* nrm = (float*)w;           w += (size_t)NB * NF * 4;
    float* vk = (float*)w;            w += 64;
    float* thr = (float*)w;           w += 64;
    w = (char*)(((uintptr_t)w + 255) & ~(uintptr_t)255);
    bf16* S = (bf16*)w;               w += (size_t)NB * FP * FP * 2;    // 75.8 MB
    bf16* Xb = (bf16*)w;              w += (size_t)NB * FP * 256 * 2;   // 8.9 MB
    bf16* K1 = (bf16*)w;              w += (size_t)NB * FP * 256 * 2;
    bf16* K2 = (bf16*)w;              w += (size_t)NB * FP * 256 * 2;
    bf16* Vt = (bf16*)w;              w += (size_t)NB * 256 * FP * 2;

    fft_fwd_kernel<<<NB * NC, 256, 0, stream>>>(x_in, Xf);
    xpack_kernel<<<(NB * FP * 256 + 255) / 256, 256, 0, stream>>>(Xf, Xb);
    kvpack_kernel<<<NB * FP, 128, 0, stream>>>(Xf, W_K, b_K, W_V, b_V, K1, K2, Vt);
    energy_kernel<<<(NB * NF + 255) / 256, 256, 0, stream>>>(Xf, energy);
    median_kernel<<<NB * 9, 256, 0, stream>>>(energy, med);
    norm_kernel<<<(NB * NF + 255) / 256, 256, 0, stream>>>(energy, med, nrm);
    select_kernel<<<(NB * NF + 255) / 256, 256, 0, stream>>>(nrm, qpar, vk);
    thresh_kernel<<<1, 64, 0, stream>>>(vk, qpar, thr);
    score_kernel<<<NB * 17 * 17, 256, 0, stream>>>(Xb, K1, K2, S);
    softmax_kernel<<<NB * NF, 256, 0, stream>>>(S);
    context_kernel<<<NB * 33, 256, 0, stream>>>(S, Vt, Ctx);
    hifreq_kernel<<<(NB * NF * NC + 255) / 256, 256, 0, stream>>>(Ctx, Xf, nrm, thr, w_high);
    fft_inv_kernel<<<NB * NC, 256, 0, stream>>>(Ctx, out);
}

// Round 4
// 800.421 us; speedup vs baseline: 4.1662x; 1.5346x over previous
//
#include <hip/hip_runtime.h>
#include <math.h>

#define NB 8
#define NC 128
#define NT 4096
#define NF 2049
#define FP 2176   // padded F = 17*128
#define LDP 72    // LDS row pitch (64 + 8 bf16) -> 144 B, conflict-free phases

typedef __bf16 bf16;
typedef __bf16 bf16x8 __attribute__((ext_vector_type(8)));
typedef float f32x4 __attribute__((ext_vector_type(4)));

// ---------------------------------------------------------------------------
// In-place radix-2 DIT FFT, length 4096, bit-reversed input. 256 threads.
// ---------------------------------------------------------------------------
__device__ __forceinline__ void fft4096(float2* buf) {
    for (int half = 1; half < NT; half <<= 1) {
        __syncthreads();
        const float fac = -(float)M_PI / (float)half;
        for (int t = threadIdx.x; t < NT / 2; t += 256) {
            int pos = t & (half - 1);
            int i = 2 * t - pos;
            int j = i + half;
            float sw, cw;
            __sincosf(fac * (float)pos, &sw, &cw);
            float2 u = buf[i], v = buf[j];
            float vr = v.x * cw - v.y * sw;
            float vi = v.x * sw + v.y * cw;
            buf[i] = make_float2(u.x + vr, u.y + vi);
            buf[j] = make_float2(u.x - vr, u.y - vi);
        }
    }
    __syncthreads();
}

__global__ __launch_bounds__(256) void fft_fwd_kernel(const float* __restrict__ x_in,
                                                      float* __restrict__ Xf) {
    __shared__ float2 buf[NT];
    int bc = blockIdx.x, b = bc >> 7, c = bc & 127;
    const float* xrow = x_in + (size_t)bc * NT;
    for (int i = threadIdx.x; i < NT; i += 256) {
        int r = __brev((unsigned)i) >> 20;
        buf[r] = make_float2(xrow[i], 0.0f);
    }
    fft4096(buf);
    const float inv = 1.0f / 64.0f;
    for (int f = threadIdx.x; f < NF; f += 256) {
        float2 v = buf[f];
        size_t o = ((size_t)b * NF + f) * (2 * NC) + 2 * c;
        Xf[o] = v.x * inv;
        Xf[o + 1] = v.y * inv;
    }
}

// Xf fp32 (B,NF,256) -> Xb bf16 (B,FP,256), pad rows zero
__global__ __launch_bounds__(256) void xpack_kernel(const float* __restrict__ Xf,
                                                    bf16* __restrict__ Xb) {
    int idx = blockIdx.x * 256 + threadIdx.x;
    if (idx >= NB * FP * 256) return;
    int k = idx & 255;
    int fp = (idx >> 8) % FP;
    int b = idx / (FP * 256);
    float v = (fp < NF) ? Xf[((size_t)b * NF + fp) * 256 + k] : 0.f;
    Xb[idx] = (bf16)v;
}

// K,V rows; writes packed bf16:
//  K1[g, 2c]=Kr, [2c+1]=-Ki ; K2[g,2c]=Ki, [2c+1]=Kr ; Vt[j, g] (transposed)
__global__ __launch_bounds__(128) void kvpack_kernel(const float* __restrict__ Xf,
                                                     const float* __restrict__ W_K,
                                                     const float* __restrict__ b_K,
                                                     const float* __restrict__ W_V,
                                                     const float* __restrict__ b_V,
                                                     bf16* __restrict__ K1,
                                                     bf16* __restrict__ K2,
                                                     bf16* __restrict__ Vt) {
    __shared__ float xr[2 * NC];
    int bg = blockIdx.x;
    int b = bg / FP, g = bg % FP;
    int j = threadIdx.x;
    float kr = 0.f, ki = 0.f, vr = 0.f, vi = 0.f;
    if (g < NF) {
        const float* xrow = Xf + ((size_t)b * NF + g) * 2 * NC;
        for (int i = j; i < 2 * NC; i += 128) xr[i] = xrow[i];
        __syncthreads();
        const float* wk = W_K + j * NC;
        const float* wv = W_V + j * NC;
        for (int c = 0; c < NC; ++c) {
            float w1 = wk[c], w2 = wv[c];
            float xre = xr[2 * c], xim = xr[2 * c + 1];
            kr += w1 * xre; ki += w1 * xim;
            vr += w2 * xre; vi += w2 * xim;
        }
        if (g == 0) { kr += 64.0f * b_K[j]; vr += 64.0f * b_V[j]; }
    }
    size_t o = (size_t)bg * 2 * NC;
    K1[o + 2 * j] = (bf16)kr;  K1[o + 2 * j + 1] = (bf16)(-ki);
    K2[o + 2 * j] = (bf16)ki;  K2[o + 2 * j + 1] = (bf16)kr;
    Vt[((size_t)b * 256 + 2 * j) * FP + g] = (bf16)vr;
    Vt[((size_t)b * 256 + 2 * j + 1) * FP + g] = (bf16)vi;
}

__global__ __launch_bounds__(256) void energy_kernel(const float* __restrict__ Xf,
                                                     float* __restrict__ energy) {
    int idx = blockIdx.x * 256 + threadIdx.x;
    if (idx >= NB * NF) return;
    const float4* row = (const float4*)(Xf + (size_t)idx * 2 * NC);
    float e = 0.f;
    for (int i = 0; i < 64; ++i) {
        float4 v = row[i];
        e += v.x * v.x + v.y * v.y + v.z * v.z + v.w * v.w;
    }
    energy[idx] = e;
}

// per-batch median: batch x 9 chunk blocks, float4 LDS rank loop
__global__ __launch_bounds__(256) void median_kernel(const float* __restrict__ energy,
                                                     float* __restrict__ med) {
    int blk = blockIdx.x;
    int b = blk / 9, chunk = blk % 9;
    __shared__ __align__(16) float e[2052];
    for (int i = threadIdx.x; i < 2052; i += 256)
        e[i] = (i < NF) ? energy[b * NF + i] : INFINITY;
    __syncthreads();
    int i = chunk * 256 + threadIdx.x;
    float ei = (i < NF) ? e[i] : 0.f;
    int rank = 0;
#pragma unroll 4
    for (int j4 = 0; j4 < 513; ++j4) {
        float4 v = ((const float4*)e)[j4];
        int j = j4 * 4;
        rank += (v.x < ei) || (v.x == ei && j + 0 < i);
        rank += (v.y < ei) || (v.y == ei && j + 1 < i);
        rank += (v.z < ei) || (v.z == ei && j + 2 < i);
        rank += (v.w < ei) || (v.w == ei && j + 3 < i);
    }
    if (i < NF && rank == 1024) med[b] = ei;
}

__global__ __launch_bounds__(256) void norm_kernel(const float* __restrict__ energy,
                                                   const float* __restrict__ med,
                                                   float* __restrict__ nrm) {
    int idx = blockIdx.x * 256 + threadIdx.x;
    if (idx >= NB * NF) return;
    int b = idx / NF;
    nrm[idx] = energy[idx] / (med[b] + 1e-6f);
}

// ---------------------------------------------------------------------------
// Global quantile: 2-D distributed rank selection.
// Grid = 65 candidate-blocks x 17 data-chunks; partial ranks to rankpart.
// ---------------------------------------------------------------------------
__global__ __launch_bounds__(256) void rankpart_kernel(const float* __restrict__ nrm,
                                                       int* __restrict__ rankpart) {
    const int n = NB * NF;
    int cb = blockIdx.x / 17;
    int chunk = blockIdx.x % 17;
    __shared__ __align__(16) float cdata[1024];
    int base = chunk * 1024;
    for (int t = threadIdx.x; t < 1024; t += 256)
        cdata[t] = (base + t < n) ? nrm[base + t] : INFINITY;
    __syncthreads();
    int i = cb * 256 + threadIdx.x;
    if (i >= n) return;
    float ei = nrm[i];
    int rank = 0;
#pragma unroll 8
    for (int t4 = 0; t4 < 256; ++t4) {
        float4 v = ((const float4*)cdata)[t4];
        int j = base + t4 * 4;
        rank += (v.x < ei) || (v.x == ei && j + 0 < i);
        rank += (v.y < ei) || (v.y == ei && j + 1 < i);
        rank += (v.z < ei) || (v.z == ei && j + 2 < i);
        rank += (v.w < ei) || (v.w == ei && j + 3 < i);
    }
    rankpart[(size_t)i * 17 + chunk] = rank;
}

__global__ __launch_bounds__(256) void rankreduce_kernel(const int* __restrict__ rankpart,
                                                         const float* __restrict__ nrm,
                                                         const float* __restrict__ q,
                                                         float* __restrict__ vk) {
    const int n = NB * NF;
    int i = blockIdx.x * 256 + threadIdx.x;
    if (i >= n) return;
    int rank = 0;
    const int* rp = rankpart + (size_t)i * 17;
#pragma unroll
    for (int c = 0; c < 17; ++c) rank += rp[c];
    double pos = (double)q[0] * (double)(n - 1);
    int k0 = (int)floor(pos);
    int k1 = min(k0 + 1, n - 1);
    if (rank == k0) vk[0] = nrm[i];
    if (rank == k1) vk[1] = nrm[i];
}

__global__ void thresh_kernel(const float* __restrict__ vk,
                              const float* __restrict__ q,
                              float* __restrict__ thr) {
    if (threadIdx.x == 0 && blockIdx.x == 0) {
        const int n = NB * NF;
        double pos = (double)q[0] * (double)(n - 1);
        double k0 = floor(pos);
        double frac = pos - k0;
        thr[0] = (float)((double)vk[0] + ((double)vk[1] - (double)vk[0]) * frac);
    }
}

// ---------------------------------------------------------------------------
// Scores via MFMA: S[f,g] = |X[f,:].K[g,:]| * C^-0.5, as two K=256 real GEMMs.
// ---------------------------------------------------------------------------
__global__ __launch_bounds__(256, 2) void score_kernel(const bf16* __restrict__ Xb,
                                                       const bf16* __restrict__ K1,
                                                       const bf16* __restrict__ K2,
                                                       bf16* __restrict__ S) {
    __shared__ bf16 As[128][LDP];
    __shared__ bf16 B1s[128][LDP];
    __shared__ bf16 B2s[128][LDP];
    int blk = blockIdx.x;
    int b = blk / (17 * 17);
    int t2 = blk % (17 * 17);
    int f0 = (t2 / 17) * 128;
    int g0 = (t2 % 17) * 128;
    int tid = threadIdx.x;
    int wave = tid >> 6, lane = tid & 63;
    int m = lane & 15, quad = lane >> 4;
    int row_off = (wave & 1) * 64, col_off = (wave >> 1) * 64;

    f32x4 accRe[4][4] = {};
    f32x4 accIm[4][4] = {};
    const bf16* Abase = Xb + ((size_t)b * FP + f0) * 256;
    const bf16* B1base = K1 + ((size_t)b * FP + g0) * 256;
    const bf16* B2base = K2 + ((size_t)b * FP + g0) * 256;
    int r0 = tid >> 3, c0 = (tid & 7) * 8;

    for (int kk = 0; kk < 256; kk += 64) {
        __syncthreads();
#pragma unroll
        for (int s = 0; s < 4; ++s) {
            int r = r0 + 32 * s;
            *(bf16x8*)&As[r][c0] = *(const bf16x8*)&Abase[(size_t)r * 256 + kk + c0];
            *(bf16x8*)&B1s[r][c0] = *(const bf16x8*)&B1base[(size_t)r * 256 + kk + c0];
            *(bf16x8*)&B2s[r][c0] = *(const bf16x8*)&B2base[(size_t)r * 256 + kk + c0];
        }
        __syncthreads();
#pragma unroll
        for (int k2 = 0; k2 < 64; k2 += 32) {
            bf16x8 a[4], b1[4], b2[4];
            int kq = k2 + quad * 8;
#pragma unroll
            for (int i = 0; i < 4; ++i) a[i] = *(const bf16x8*)&As[row_off + i * 16 + m][kq];
#pragma unroll
            for (int j = 0; j < 4; ++j) b1[j] = *(const bf16x8*)&B1s[col_off + j * 16 + m][kq];
#pragma unroll
            for (int j = 0; j < 4; ++j) b2[j] = *(const bf16x8*)&B2s[col_off + j * 16 + m][kq];
#pragma unroll
            for (int i = 0; i < 4; ++i)
#pragma unroll
                for (int j = 0; j < 4; ++j) {
                    accRe[i][j] = __builtin_amdgcn_mfma_f32_16x16x32_bf16(a[i], b1[j], accRe[i][j], 0, 0, 0);
                    accIm[i][j] = __builtin_amdgcn_mfma_f32_16x16x32_bf16(a[i], b2[j], accIm[i][j], 0, 0, 0);
                }
        }
    }
    const float SCALE = 0.08838834764831845f;  // 1/sqrt(128)
    bf16* Sb = S + (size_t)b * FP * FP;
#pragma unroll
    for (int i = 0; i < 4; ++i)
#pragma unroll
        for (int j = 0; j < 4; ++j)
#pragma unroll
            for (int r = 0; r < 4; ++r) {
                int row = f0 + row_off + i * 16 + quad * 4 + r;
                int col = g0 + col_off + j * 16 + m;
                float re = accRe[i][j][r], im = accIm[i][j][r];
                Sb[(size_t)row * FP + col] = (bf16)(sqrtf(re * re + im * im) * SCALE);
            }
}

// row softmax in place (bf16), zero pad cols
__global__ __launch_bounds__(256) void softmax_kernel(bf16* __restrict__ S) {
    int bf = blockIdx.x;
    int b = bf / NF, f = bf % NF;
    bf16* row = S + ((size_t)b * FP + f) * FP;
    __shared__ float red[256];
    float mx = -1e30f;
    for (int g = threadIdx.x; g < NF; g += 256) mx = fmaxf(mx, (float)row[g]);
    red[threadIdx.x] = mx;
    __syncthreads();
    for (int s = 128; s > 0; s >>= 1) {
        if (threadIdx.x < s) red[threadIdx.x] = fmaxf(red[threadIdx.x], red[threadIdx.x + s]);
        __syncthreads();
    }
    float mval = red[0];
    __syncthreads();
    float sum = 0.f;
    for (int g = threadIdx.x; g < NF; g += 256) sum += __expf((float)row[g] - mval);
    red[threadIdx.x] = sum;
    __syncthreads();
    for (int s = 128; s > 0; s >>= 1) {
        if (threadIdx.x < s) red[threadIdx.x] += red[threadIdx.x + s];
        __syncthreads();
    }
    float inv = 1.f / red[0];
    for (int g = threadIdx.x; g < FP; g += 256) {
        float p = (g < NF) ? __expf((float)row[g] - mval) * inv : 0.f;
        row[g] = (bf16)p;
    }
}

// ---------------------------------------------------------------------------
// Context via MFMA: Ctx[f,j] = sum_g P[f,g] Vt[j,g].
// ---------------------------------------------------------------------------
__global__ __launch_bounds__(256, 2) void context_kernel(const bf16* __restrict__ P,
                                                         const bf16* __restrict__ Vt,
                                                         float* __restrict__ Ctx) {
    __shared__ bf16 Ps[64][LDP];
    __shared__ bf16 Vs[256][LDP];
    int blk = blockIdx.x;
    int b = blk / 33;
    int f0 = (blk % 33) * 64;
    int tid = threadIdx.x;
    int wave = tid >> 6, lane = tid & 63;
    int m = lane & 15, quad = lane >> 4;
    int col_off = wave * 64;

    f32x4 acc[4][4] = {};
    const bf16* Pbase = P + ((size_t)b * FP + f0) * FP;
    const bf16* Vbase = Vt + (size_t)b * 256 * FP;
    int r0 = tid >> 3, c0 = (tid & 7) * 8;

    for (int kk = 0; kk < FP; kk += 64) {
        __syncthreads();
#pragma unroll
        for (int s = 0; s < 2; ++s) {
            int r = r0 + 32 * s;
            *(bf16x8*)&Ps[r][c0] = *(const bf16x8*)&Pbase[(size_t)r * FP + kk + c0];
        }
#pragma unroll
        for (int s = 0; s < 8; ++s) {
            int r = r0 + 32 * s;
            *(bf16x8*)&Vs[r][c0] = *(const bf16x8*)&Vbase[(size_t)r * FP + kk + c0];
        }
        __syncthreads();
#pragma unroll
        for (int k2 = 0; k2 < 64; k2 += 32) {
            bf16x8 a[4], bb[4];
            int kq = k2 + quad * 8;
#pragma unroll
            for (int i = 0; i < 4; ++i) a[i] = *(const bf16x8*)&Ps[i * 16 + m][kq];
#pragma unroll
            for (int j = 0; j < 4; ++j) bb[j] = *(const bf16x8*)&Vs[col_off + j * 16 + m][kq];
#pragma unroll
            for (int i = 0; i < 4; ++i)
#pragma unroll
                for (int j = 0; j < 4; ++j)
                    acc[i][j] = __builtin_amdgcn_mfma_f32_16x16x32_bf16(a[i], bb[j], acc[i][j], 0, 0, 0);
        }
    }
#pragma unroll
    for (int i = 0; i < 4; ++i)
#pragma unroll
        for (int j = 0; j < 4; ++j)
#pragma unroll
            for (int r = 0; r < 4; ++r) {
                int row = f0 + i * 16 + quad * 4 + r;
                int col = col_off + j * 16 + m;
                if (row < NF) Ctx[((size_t)b * NF + row) * 256 + col] = acc[i][j][r];
            }
}

// ctx += mask * X * (w_high[:,0] + i w_high[:,1])
__global__ __launch_bounds__(256) void hifreq_kernel(float* __restrict__ Ctx,
                                                     const float* __restrict__ Xf,
                                                     const float* __restrict__ nrm,
                                                     const float* __restrict__ thr,
                                                     const float* __restrict__ w_high) {
    int idx = blockIdx.x * 256 + threadIdx.x;
    if (idx >= NB * NF * NC) return;
    int c = idx & 127;
    int bf = idx >> 7;
    if (nrm[bf] > thr[0]) {
        float wr = w_high[2 * c], wi = w_high[2 * c + 1];
        size_t o = (size_t)bf * 2 * NC + 2 * c;
        float xre = Xf[o], xim = Xf[o + 1];
        Ctx[o] += xre * wr - xim * wi;
        Ctx[o + 1] += xre * wi + xim * wr;
    }
}

__global__ __launch_bounds__(256) void fft_inv_kernel(const float* __restrict__ Ctx,
                                                      float* __restrict__ out) {
    __shared__ float2 buf[NT];
    int bc = blockIdx.x, b = bc >> 7, c = bc & 127;
    const float* base = Ctx + (size_t)b * NF * 2 * NC + 2 * c;
    for (int f = threadIdx.x; f < NT; f += 256) {
        float re, im;
        if (f <= NT / 2) {
            re = base[(size_t)f * 2 * NC];
            im = -base[(size_t)f * 2 * NC + 1];
        } else {
            int g = NT - f;
            re = base[(size_t)g * 2 * NC];
            im = base[(size_t)g * 2 * NC + 1];
        }
        int r = __brev((unsigned)f) >> 20;
        buf[r] = make_float2(re, im);
    }
    fft4096(buf);
    float* orow = out + (size_t)bc * NT;
    const float inv = 1.0f / 64.0f;
    for (int n = threadIdx.x; n < NT; n += 256) orow[n] = buf[n].x * inv;
}

extern "C" void kernel_launch(void* const* d_in, const int* in_sizes, int n_in,
                              void* d_out, int out_size, void* d_ws, size_t ws_size,
                              hipStream_t stream) {
    const float* x_in = (const float*)d_in[0];
    const float* W_K = (const float*)d_in[1];
    const float* b_K = (const float*)d_in[2];
    const float* W_V = (const float*)d_in[3];
    const float* b_V = (const float*)d_in[4];
    const float* w_high = (const float*)d_in[5];
    const float* qpar = (const float*)d_in[6];
    float* out = (float*)d_out;

    char* w = (char*)d_ws;
    const size_t SPECB = (size_t)NB * NF * 256 * 4;       // 16.8 MB
    float* Xf = (float*)w;            w += SPECB;
    float* Ctx = (float*)w;           w += SPECB;
    float* energy = (float*)w;        w += (size_t)NB * NF * 4;
    float* med = (float*)w;           w += 64;
    float* nrm = (float*)w;           w += (size_t)NB * NF * 4;
    float* vk = (float*)w;            w += 64;
    float* thr = (float*)w;           w += 64;
    w = (char*)(((uintptr_t)w + 255) & ~(uintptr_t)255);
    int* rankpart = (int*)w;          w += (size_t)16640 * 17 * 4;      // 1.1 MB
    w = (char*)(((uintptr_t)w + 255) & ~(uintptr_t)255);
    bf16* S = (bf16*)w;               w += (size_t)NB * FP * FP * 2;    // 75.8 MB
    bf16* Xb = (bf16*)w;              w += (size_t)NB * FP * 256 * 2;   // 8.9 MB
    bf16* K1 = (bf16*)w;              w += (size_t)NB * FP * 256 * 2;
    bf16* K2 = (bf16*)w;              w += (size_t)NB * FP * 256 * 2;
    bf16* Vt = (bf16*)w;              w += (size_t)NB * 256 * FP * 2;

    fft_fwd_kernel<<<NB * NC, 256, 0, stream>>>(x_in, Xf);
    xpack_kernel<<<(NB * FP * 256 + 255) / 256, 256, 0, stream>>>(Xf, Xb);
    kvpack_kernel<<<NB * FP, 128, 0, stream>>>(Xf, W_K, b_K, W_V, b_V, K1, K2, Vt);
    energy_kernel<<<(NB * NF + 255) / 256, 256, 0, stream>>>(Xf, energy);
    median_kernel<<<NB * 9, 256, 0, stream>>>(energy, med);
    norm_kernel<<<(NB * NF + 255) / 256, 256, 0, stream>>>(energy, med, nrm);
    rankpart_kernel<<<65 * 17, 256, 0, stream>>>(nrm, rankpart);
    rankreduce_kernel<<<65, 256, 0, stream>>>(rankpart, nrm, qpar, vk);
    thresh_kernel<<<1, 64, 0, stream>>>(vk, qpar, thr);
    score_kernel<<<NB * 17 * 17, 256, 0, stream>>>(Xb, K1, K2, S);
    softmax_kernel<<<NB * NF, 256, 0, stream>>>(S);
    context_kernel<<<NB * 33, 256, 0, stream>>>(S, Vt, Ctx);
    hifreq_kernel<<<(NB * NF * NC + 255) / 256, 256, 0, stream>>>(Ctx, Xf, nrm, thr, w_high);
    fft_inv_kernel<<<NB * NC, 256, 0, stream>>>(Ctx, out);
}

// Round 5
// 571.253 us; speedup vs baseline: 5.8376x; 1.4012x over previous
//
#include <hip/hip_runtime.h>
#include <math.h>

#define NB 8
#define NC 128
#define NT 4096
#define NF 2049
#define FP 2176   // padded F = 17*128
#define LDP 72    // LDS row pitch (64 + 8 bf16) -> 144 B, conflict-free phases

typedef __bf16 bf16;
typedef __bf16 bf16x8 __attribute__((ext_vector_type(8)));
typedef float f32x4 __attribute__((ext_vector_type(4)));

// ---------------------------------------------------------------------------
// In-place radix-2 DIT FFT, length 4096, bit-reversed input. 256 threads.
// ---------------------------------------------------------------------------
__device__ __forceinline__ void fft4096(float2* buf) {
    for (int half = 1; half < NT; half <<= 1) {
        __syncthreads();
        const float fac = -(float)M_PI / (float)half;
        for (int t = threadIdx.x; t < NT / 2; t += 256) {
            int pos = t & (half - 1);
            int i = 2 * t - pos;
            int j = i + half;
            float sw, cw;
            __sincosf(fac * (float)pos, &sw, &cw);
            float2 u = buf[i], v = buf[j];
            float vr = v.x * cw - v.y * sw;
            float vi = v.x * sw + v.y * cw;
            buf[i] = make_float2(u.x + vr, u.y + vi);
            buf[j] = make_float2(u.x - vr, u.y - vi);
        }
    }
    __syncthreads();
}

__global__ __launch_bounds__(256) void fft_fwd_kernel(const float* __restrict__ x_in,
                                                      float* __restrict__ Xf) {
    __shared__ float2 buf[NT];
    int bc = blockIdx.x, b = bc >> 7, c = bc & 127;
    const float* xrow = x_in + (size_t)bc * NT;
    for (int i = threadIdx.x; i < NT; i += 256) {
        int r = __brev((unsigned)i) >> 20;
        buf[r] = make_float2(xrow[i], 0.0f);
    }
    fft4096(buf);
    const float inv = 1.0f / 64.0f;
    for (int f = threadIdx.x; f < NF; f += 256) {
        float2 v = buf[f];
        size_t o = ((size_t)b * NF + f) * (2 * NC) + 2 * c;
        Xf[o] = v.x * inv;
        Xf[o + 1] = v.y * inv;
    }
}

// Xf fp32 (B,NF,256) -> Xb bf16 (B,FP,256), pad rows zero
__global__ __launch_bounds__(256) void xpack_kernel(const float* __restrict__ Xf,
                                                    bf16* __restrict__ Xb) {
    int idx = blockIdx.x * 256 + threadIdx.x;
    if (idx >= NB * FP * 256) return;
    int k = idx & 255;
    int fp = (idx >> 8) % FP;
    int b = idx / (FP * 256);
    float v = (fp < NF) ? Xf[((size_t)b * NF + fp) * 256 + k] : 0.f;
    Xb[idx] = (bf16)v;
}

// ---------------------------------------------------------------------------
// Packed weight matrices (bf16):
//  Wkk (512 x 256): rows 0..255 produce K1 (Kr,-Ki interleaved),
//                   rows 256..511 produce K2 (Ki,Kr interleaved)
//  Av  (256 x 256): rows produce Vt (Vr,Vi interleaved, row-major over n=2j)
// ---------------------------------------------------------------------------
__global__ __launch_bounds__(256) void wpack_kernel(const float* __restrict__ W_K,
                                                    const float* __restrict__ W_V,
                                                    bf16* __restrict__ Wkk,
                                                    bf16* __restrict__ Av) {
    int idx = blockIdx.x * 256 + threadIdx.x;
    if (idx < 512 * 256) {
        int n = idx >> 8, k = idx & 255;
        int c = k >> 1;
        float v = 0.f;
        if (n < 256) {  // K1: n=2j even k -> W ; n=2j+1 odd k -> -W
            int j = n >> 1;
            if (!(n & 1) && !(k & 1)) v = W_K[j * NC + c];
            else if ((n & 1) && (k & 1)) v = -W_K[j * NC + c];
        } else {        // K2: n=2j odd k -> W ; n=2j+1 even k -> W
            int j = (n - 256) >> 1;
            if (!(n & 1) && (k & 1)) v = W_K[j * NC + c];
            else if ((n & 1) && !(k & 1)) v = W_K[j * NC + c];
        }
        Wkk[idx] = (bf16)v;
    }
    if (idx < 256 * 256) {
        int n = idx >> 8, k = idx & 255;
        int j = n >> 1, c = k >> 1;
        float v = 0.f;
        if (!(n & 1) && !(k & 1)) v = W_V[j * NC + c];
        else if ((n & 1) && (k & 1)) v = W_V[j * NC + c];
        Av[idx] = (bf16)v;
    }
}

// K12[(b*FP+g)*512 + n] = sum_k Xb[b,g,k] * Wkk[n,k]
__global__ __launch_bounds__(256, 2) void kvgemm_kernel(const bf16* __restrict__ Xb,
                                                        const bf16* __restrict__ Wkk,
                                                        bf16* __restrict__ K12) {
    __shared__ bf16 As[128][LDP];
    __shared__ bf16 Bs[128][LDP];
    int blk = blockIdx.x;
    int b = blk / (17 * 4);
    int t2 = blk % (17 * 4);
    int g0 = (t2 >> 2) * 128;
    int n0 = (t2 & 3) * 128;
    int tid = threadIdx.x;
    int wave = tid >> 6, lane = tid & 63;
    int m = lane & 15, quad = lane >> 4;
    int row_off = (wave & 1) * 64, col_off = (wave >> 1) * 64;

    f32x4 acc[4][4] = {};
    const bf16* Abase = Xb + ((size_t)b * FP + g0) * 256;
    const bf16* Bbase = Wkk + (size_t)n0 * 256;
    int r0 = tid >> 3, c0 = (tid & 7) * 8;

    for (int kk = 0; kk < 256; kk += 64) {
        __syncthreads();
#pragma unroll
        for (int s = 0; s < 4; ++s) {
            int r = r0 + 32 * s;
            *(bf16x8*)&As[r][c0] = *(const bf16x8*)&Abase[(size_t)r * 256 + kk + c0];
            *(bf16x8*)&Bs[r][c0] = *(const bf16x8*)&Bbase[(size_t)r * 256 + kk + c0];
        }
        __syncthreads();
#pragma unroll
        for (int k2 = 0; k2 < 64; k2 += 32) {
            bf16x8 a[4], bb[4];
            int kq = k2 + quad * 8;
#pragma unroll
            for (int i = 0; i < 4; ++i) a[i] = *(const bf16x8*)&As[row_off + i * 16 + m][kq];
#pragma unroll
            for (int j = 0; j < 4; ++j) bb[j] = *(const bf16x8*)&Bs[col_off + j * 16 + m][kq];
#pragma unroll
            for (int i = 0; i < 4; ++i)
#pragma unroll
                for (int j = 0; j < 4; ++j)
                    acc[i][j] = __builtin_amdgcn_mfma_f32_16x16x32_bf16(a[i], bb[j], acc[i][j], 0, 0, 0);
        }
    }
#pragma unroll
    for (int i = 0; i < 4; ++i)
#pragma unroll
        for (int j = 0; j < 4; ++j)
#pragma unroll
            for (int r = 0; r < 4; ++r) {
                int row = g0 + row_off + i * 16 + quad * 4 + r;
                int col = n0 + col_off + j * 16 + m;
                K12[((size_t)b * FP + row) * 512 + col] = (bf16)acc[i][j][r];
            }
}

// Vt[(b*256+n)*FP + g] = sum_k Av[n,k] * Xb[b,g,k]
__global__ __launch_bounds__(256, 2) void vtgemm_kernel(const bf16* __restrict__ Av,
                                                        const bf16* __restrict__ Xb,
                                                        bf16* __restrict__ Vt) {
    __shared__ bf16 As[128][LDP];
    __shared__ bf16 Bs[128][LDP];
    int blk = blockIdx.x;
    int b = blk / (17 * 2);
    int t2 = blk % (17 * 2);
    int g0 = (t2 >> 1) * 128;
    int n0 = (t2 & 1) * 128;
    int tid = threadIdx.x;
    int wave = tid >> 6, lane = tid & 63;
    int m = lane & 15, quad = lane >> 4;
    int row_off = (wave & 1) * 64, col_off = (wave >> 1) * 64;

    f32x4 acc[4][4] = {};
    const bf16* Abase = Av + (size_t)n0 * 256;
    const bf16* Bbase = Xb + ((size_t)b * FP + g0) * 256;
    int r0 = tid >> 3, c0 = (tid & 7) * 8;

    for (int kk = 0; kk < 256; kk += 64) {
        __syncthreads();
#pragma unroll
        for (int s = 0; s < 4; ++s) {
            int r = r0 + 32 * s;
            *(bf16x8*)&As[r][c0] = *(const bf16x8*)&Abase[(size_t)r * 256 + kk + c0];
            *(bf16x8*)&Bs[r][c0] = *(const bf16x8*)&Bbase[(size_t)r * 256 + kk + c0];
        }
        __syncthreads();
#pragma unroll
        for (int k2 = 0; k2 < 64; k2 += 32) {
            bf16x8 a[4], bb[4];
            int kq = k2 + quad * 8;
#pragma unroll
            for (int i = 0; i < 4; ++i) a[i] = *(const bf16x8*)&As[row_off + i * 16 + m][kq];
#pragma unroll
            for (int j = 0; j < 4; ++j) bb[j] = *(const bf16x8*)&Bs[col_off + j * 16 + m][kq];
#pragma unroll
            for (int i = 0; i < 4; ++i)
#pragma unroll
                for (int j = 0; j < 4; ++j)
                    acc[i][j] = __builtin_amdgcn_mfma_f32_16x16x32_bf16(a[i], bb[j], acc[i][j], 0, 0, 0);
        }
    }
#pragma unroll
    for (int i = 0; i < 4; ++i)
#pragma unroll
        for (int j = 0; j < 4; ++j)
#pragma unroll
            for (int r = 0; r < 4; ++r) {
                int row = n0 + row_off + i * 16 + quad * 4 + r;
                int col = g0 + col_off + j * 16 + m;
                Vt[((size_t)b * 256 + row) * FP + col] = (bf16)acc[i][j][r];
            }
}

// DC-bin bias: rfft(const b, ortho) = sqrt(N)*b at f=0 only (re part)
__global__ __launch_bounds__(128) void biasfix_kernel(const float* __restrict__ b_K,
                                                      const float* __restrict__ b_V,
                                                      bf16* __restrict__ K12,
                                                      bf16* __restrict__ Vt) {
    int b = blockIdx.x;
    int j = threadIdx.x;
    float bk = 64.0f * b_K[j], bv = 64.0f * b_V[j];
    size_t o = (size_t)b * FP * 512;
    K12[o + 2 * j] = (bf16)((float)K12[o + 2 * j] + bk);              // K1 re
    K12[o + 256 + 2 * j + 1] = (bf16)((float)K12[o + 256 + 2 * j + 1] + bk);  // K2 re slot
    size_t ov = ((size_t)b * 256 + 2 * j) * FP;
    Vt[ov] = (bf16)((float)Vt[ov] + bv);                              // V re, g=0
}

__global__ __launch_bounds__(256) void energy_kernel(const float* __restrict__ Xf,
                                                     float* __restrict__ energy) {
    int idx = blockIdx.x * 256 + threadIdx.x;
    if (idx >= NB * NF) return;
    const float4* row = (const float4*)(Xf + (size_t)idx * 2 * NC);
    float e = 0.f;
    for (int i = 0; i < 64; ++i) {
        float4 v = row[i];
        e += v.x * v.x + v.y * v.y + v.z * v.z + v.w * v.w;
    }
    energy[idx] = e;
}

// per-batch median: batch x 9 chunk blocks, float4 LDS rank loop
__global__ __launch_bounds__(256) void median_kernel(const float* __restrict__ energy,
                                                     float* __restrict__ med) {
    int blk = blockIdx.x;
    int b = blk / 9, chunk = blk % 9;
    __shared__ __align__(16) float e[2052];
    for (int i = threadIdx.x; i < 2052; i += 256)
        e[i] = (i < NF) ? energy[b * NF + i] : INFINITY;
    __syncthreads();
    int i = chunk * 256 + threadIdx.x;
    float ei = (i < NF) ? e[i] : 0.f;
    int rank = 0;
#pragma unroll 4
    for (int j4 = 0; j4 < 513; ++j4) {
        float4 v = ((const float4*)e)[j4];
        int j = j4 * 4;
        rank += (v.x < ei) || (v.x == ei && j + 0 < i);
        rank += (v.y < ei) || (v.y == ei && j + 1 < i);
        rank += (v.z < ei) || (v.z == ei && j + 2 < i);
        rank += (v.w < ei) || (v.w == ei && j + 3 < i);
    }
    if (i < NF && rank == 1024) med[b] = ei;
}

__global__ __launch_bounds__(256) void norm_kernel(const float* __restrict__ energy,
                                                   const float* __restrict__ med,
                                                   float* __restrict__ nrm) {
    int idx = blockIdx.x * 256 + threadIdx.x;
    if (idx >= NB * NF) return;
    int b = idx / NF;
    nrm[idx] = energy[idx] / (med[b] + 1e-6f);
}

// Global quantile: 2-D distributed rank selection.
__global__ __launch_bounds__(256) void rankpart_kernel(const float* __restrict__ nrm,
                                                       int* __restrict__ rankpart) {
    const int n = NB * NF;
    int cb = blockIdx.x / 17;
    int chunk = blockIdx.x % 17;
    __shared__ __align__(16) float cdata[1024];
    int base = chunk * 1024;
    for (int t = threadIdx.x; t < 1024; t += 256)
        cdata[t] = (base + t < n) ? nrm[base + t] : INFINITY;
    __syncthreads();
    int i = cb * 256 + threadIdx.x;
    if (i >= n) return;
    float ei = nrm[i];
    int rank = 0;
#pragma unroll 8
    for (int t4 = 0; t4 < 256; ++t4) {
        float4 v = ((const float4*)cdata)[t4];
        int j = base + t4 * 4;
        rank += (v.x < ei) || (v.x == ei && j + 0 < i);
        rank += (v.y < ei) || (v.y == ei && j + 1 < i);
        rank += (v.z < ei) || (v.z == ei && j + 2 < i);
        rank += (v.w < ei) || (v.w == ei && j + 3 < i);
    }
    rankpart[(size_t)i * 17 + chunk] = rank;
}

__global__ __launch_bounds__(256) void rankreduce_kernel(const int* __restrict__ rankpart,
                                                         const float* __restrict__ nrm,
                                                         const float* __restrict__ q,
                                                         float* __restrict__ vk) {
    const int n = NB * NF;
    int i = blockIdx.x * 256 + threadIdx.x;
    if (i >= n) return;
    int rank = 0;
    const int* rp = rankpart + (size_t)i * 17;
#pragma unroll
    for (int c = 0; c < 17; ++c) rank += rp[c];
    double pos = (double)q[0] * (double)(n - 1);
    int k0 = (int)floor(pos);
    int k1 = min(k0 + 1, n - 1);
    if (rank == k0) vk[0] = nrm[i];
    if (rank == k1) vk[1] = nrm[i];
}

__global__ void thresh_kernel(const float* __restrict__ vk,
                              const float* __restrict__ q,
                              float* __restrict__ thr) {
    if (threadIdx.x == 0 && blockIdx.x == 0) {
        const int n = NB * NF;
        double pos = (double)q[0] * (double)(n - 1);
        double k0 = floor(pos);
        double frac = pos - k0;
        thr[0] = (float)((double)vk[0] + ((double)vk[1] - (double)vk[0]) * frac);
    }
}

// ---------------------------------------------------------------------------
// Scores via MFMA: S[f,g] = |X[f,:].K[g,:]| * C^-0.5, K12 pitch-512 B-operand.
// ---------------------------------------------------------------------------
__global__ __launch_bounds__(256, 2) void score_kernel(const bf16* __restrict__ Xb,
                                                       const bf16* __restrict__ K12,
                                                       bf16* __restrict__ S) {
    __shared__ bf16 As[128][LDP];
    __shared__ bf16 B1s[128][LDP];
    __shared__ bf16 B2s[128][LDP];
    int blk = blockIdx.x;
    int b = blk / (17 * 17);
    int t2 = blk % (17 * 17);
    int f0 = (t2 / 17) * 128;
    int g0 = (t2 % 17) * 128;
    int tid = threadIdx.x;
    int wave = tid >> 6, lane = tid & 63;
    int m = lane & 15, quad = lane >> 4;
    int row_off = (wave & 1) * 64, col_off = (wave >> 1) * 64;

    f32x4 accRe[4][4] = {};
    f32x4 accIm[4][4] = {};
    const bf16* Abase = Xb + ((size_t)b * FP + f0) * 256;
    const bf16* Kbase = K12 + ((size_t)b * FP + g0) * 512;
    int r0 = tid >> 3, c0 = (tid & 7) * 8;

    for (int kk = 0; kk < 256; kk += 64) {
        __syncthreads();
#pragma unroll
        for (int s = 0; s < 4; ++s) {
            int r = r0 + 32 * s;
            *(bf16x8*)&As[r][c0] = *(const bf16x8*)&Abase[(size_t)r * 256 + kk + c0];
            *(bf16x8*)&B1s[r][c0] = *(const bf16x8*)&Kbase[(size_t)r * 512 + kk + c0];
            *(bf16x8*)&B2s[r][c0] = *(const bf16x8*)&Kbase[(size_t)r * 512 + 256 + kk + c0];
        }
        __syncthreads();
#pragma unroll
        for (int k2 = 0; k2 < 64; k2 += 32) {
            bf16x8 a[4], b1[4], b2[4];
            int kq = k2 + quad * 8;
#pragma unroll
            for (int i = 0; i < 4; ++i) a[i] = *(const bf16x8*)&As[row_off + i * 16 + m][kq];
#pragma unroll
            for (int j = 0; j < 4; ++j) b1[j] = *(const bf16x8*)&B1s[col_off + j * 16 + m][kq];
#pragma unroll
            for (int j = 0; j < 4; ++j) b2[j] = *(const bf16x8*)&B2s[col_off + j * 16 + m][kq];
#pragma unroll
            for (int i = 0; i < 4; ++i)
#pragma unroll
                for (int j = 0; j < 4; ++j) {
                    accRe[i][j] = __builtin_amdgcn_mfma_f32_16x16x32_bf16(a[i], b1[j], accRe[i][j], 0, 0, 0);
                    accIm[i][j] = __builtin_amdgcn_mfma_f32_16x16x32_bf16(a[i], b2[j], accIm[i][j], 0, 0, 0);
                }
        }
    }
    const float SCALE = 0.08838834764831845f;  // 1/sqrt(128)
    bf16* Sb = S + (size_t)b * FP * FP;
#pragma unroll
    for (int i = 0; i < 4; ++i)
#pragma unroll
        for (int j = 0; j < 4; ++j)
#pragma unroll
            for (int r = 0; r < 4; ++r) {
                int row = f0 + row_off + i * 16 + quad * 4 + r;
                int col = g0 + col_off + j * 16 + m;
                float re = accRe[i][j][r], im = accIm[i][j][r];
                Sb[(size_t)row * FP + col] = (bf16)(sqrtf(re * re + im * im) * SCALE);
            }
}

// row softmax in place (bf16), zero pad cols
__global__ __launch_bounds__(256) void softmax_kernel(bf16* __restrict__ S) {
    int bf = blockIdx.x;
    int b = bf / NF, f = bf % NF;
    bf16* row = S + ((size_t)b * FP + f) * FP;
    __shared__ float red[256];
    float mx = -1e30f;
    for (int g = threadIdx.x; g < NF; g += 256) mx = fmaxf(mx, (float)row[g]);
    red[threadIdx.x] = mx;
    __syncthreads();
    for (int s = 128; s > 0; s >>= 1) {
        if (threadIdx.x < s) red[threadIdx.x] = fmaxf(red[threadIdx.x], red[threadIdx.x + s]);
        __syncthreads();
    }
    float mval = red[0];
    __syncthreads();
    float sum = 0.f;
    for (int g = threadIdx.x; g < NF; g += 256) sum += __expf((float)row[g] - mval);
    red[threadIdx.x] = sum;
    __syncthreads();
    for (int s = 128; s > 0; s >>= 1) {
        if (threadIdx.x < s) red[threadIdx.x] += red[threadIdx.x + s];
        __syncthreads();
    }
    float inv = 1.f / red[0];
    for (int g = threadIdx.x; g < FP; g += 256) {
        float p = (g < NF) ? __expf((float)row[g] - mval) * inv : 0.f;
        row[g] = (bf16)p;
    }
}

// ---------------------------------------------------------------------------
// Context via MFMA: Ctx[f,j] = sum_g P[f,g] Vt[j,g].
// ---------------------------------------------------------------------------
__global__ __launch_bounds__(256, 2) void context_kernel(const bf16* __restrict__ P,
                                                         const bf16* __restrict__ Vt,
                                                         float* __restrict__ Ctx) {
    __shared__ bf16 Ps[64][LDP];
    __shared__ bf16 Vs[256][LDP];
    int blk = blockIdx.x;
    int b = blk / 33;
    int f0 = (blk % 33) * 64;
    int tid = threadIdx.x;
    int wave = tid >> 6, lane = tid & 63;
    int m = lane & 15, quad = lane >> 4;
    int col_off = wave * 64;

    f32x4 acc[4][4] = {};
    const bf16* Pbase = P + ((size_t)b * FP + f0) * FP;
    const bf16* Vbase = Vt + (size_t)b * 256 * FP;
    int r0 = tid >> 3, c0 = (tid & 7) * 8;

    for (int kk = 0; kk < FP; kk += 64) {
        __syncthreads();
#pragma unroll
        for (int s = 0; s < 2; ++s) {
            int r = r0 + 32 * s;
            *(bf16x8*)&Ps[r][c0] = *(const bf16x8*)&Pbase[(size_t)r * FP + kk + c0];
        }
#pragma unroll
        for (int s = 0; s < 8; ++s) {
            int r = r0 + 32 * s;
            *(bf16x8*)&Vs[r][c0] = *(const bf16x8*)&Vbase[(size_t)r * FP + kk + c0];
        }
        __syncthreads();
#pragma unroll
        for (int k2 = 0; k2 < 64; k2 += 32) {
            bf16x8 a[4], bb[4];
            int kq = k2 + quad * 8;
#pragma unroll
            for (int i = 0; i < 4; ++i) a[i] = *(const bf16x8*)&Ps[i * 16 + m][kq];
#pragma unroll
            for (int j = 0; j < 4; ++j) bb[j] = *(const bf16x8*)&Vs[col_off + j * 16 + m][kq];
#pragma unroll
            for (int i = 0; i < 4; ++i)
#pragma unroll
                for (int j = 0; j < 4; ++j)
                    acc[i][j] = __builtin_amdgcn_mfma_f32_16x16x32_bf16(a[i], bb[j], acc[i][j], 0, 0, 0);
        }
    }
#pragma unroll
    for (int i = 0; i < 4; ++i)
#pragma unroll
        for (int j = 0; j < 4; ++j)
#pragma unroll
            for (int r = 0; r < 4; ++r) {
                int row = f0 + i * 16 + quad * 4 + r;
                int col = col_off + j * 16 + m;
                if (row < NF) Ctx[((size_t)b * NF + row) * 256 + col] = acc[i][j][r];
            }
}

// ctx += mask * X * (w_high[:,0] + i w_high[:,1])
__global__ __launch_bounds__(256) void hifreq_kernel(float* __restrict__ Ctx,
                                                     const float* __restrict__ Xf,
                                                     const float* __restrict__ nrm,
                                                     const float* __restrict__ thr,
                                                     const float* __restrict__ w_high) {
    int idx = blockIdx.x * 256 + threadIdx.x;
    if (idx >= NB * NF * NC) return;
    int c = idx & 127;
    int bf = idx >> 7;
    if (nrm[bf] > thr[0]) {
        float wr = w_high[2 * c], wi = w_high[2 * c + 1];
        size_t o = (size_t)bf * 2 * NC + 2 * c;
        float xre = Xf[o], xim = Xf[o + 1];
        Ctx[o] += xre * wr - xim * wi;
        Ctx[o + 1] += xre * wi + xim * wr;
    }
}

__global__ __launch_bounds__(256) void fft_inv_kernel(const float* __restrict__ Ctx,
                                                      float* __restrict__ out) {
    __shared__ float2 buf[NT];
    int bc = blockIdx.x, b = bc >> 7, c = bc & 127;
    const float* base = Ctx + (size_t)b * NF * 2 * NC + 2 * c;
    for (int f = threadIdx.x; f < NT; f += 256) {
        float re, im;
        if (f <= NT / 2) {
            re = base[(size_t)f * 2 * NC];
            im = -base[(size_t)f * 2 * NC + 1];
        } else {
            int g = NT - f;
            re = base[(size_t)g * 2 * NC];
            im = base[(size_t)g * 2 * NC + 1];
        }
        int r = __brev((unsigned)f) >> 20;
        buf[r] = make_float2(re, im);
    }
    fft4096(buf);
    float* orow = out + (size_t)bc * NT;
    const float inv = 1.0f / 64.0f;
    for (int n = threadIdx.x; n < NT; n += 256) orow[n] = buf[n].x * inv;
}

extern "C" void kernel_launch(void* const* d_in, const int* in_sizes, int n_in,
                              void* d_out, int out_size, void* d_ws, size_t ws_size,
                              hipStream_t stream) {
    const float* x_in = (const float*)d_in[0];
    const float* W_K = (const float*)d_in[1];
    const float* b_K = (const float*)d_in[2];
    const float* W_V = (const float*)d_in[3];
    const float* b_V = (const float*)d_in[4];
    const float* w_high = (const float*)d_in[5];
    const float* qpar = (const float*)d_in[6];
    float* out = (float*)d_out;

    char* w = (char*)d_ws;
    const size_t SPECB = (size_t)NB * NF * 256 * 4;       // 16.8 MB
    float* Xf = (float*)w;            w += SPECB;
    float* Ctx = (float*)w;           w += SPECB;
    float* energy = (float*)w;        w += (size_t)NB * NF * 4;
    float* med = (float*)w;           w += 64;
    float* nrm = (float*)w;           w += (size_t)NB * NF * 4;
    float* vk = (float*)w;            w += 64;
    float* thr = (float*)w;           w += 64;
    w = (char*)(((uintptr_t)w + 255) & ~(uintptr_t)255);
    int* rankpart = (int*)w;          w += (size_t)16640 * 17 * 4;      // 1.1 MB
    w = (char*)(((uintptr_t)w + 255) & ~(uintptr_t)255);
    bf16* S = (bf16*)w;               w += (size_t)NB * FP * FP * 2;    // 75.8 MB
    bf16* Xb = (bf16*)w;              w += (size_t)NB * FP * 256 * 2;   // 8.9 MB
    bf16* K12 = (bf16*)w;             w += (size_t)NB * FP * 512 * 2;   // 17.8 MB
    bf16* Vt = (bf16*)w;              w += (size_t)NB * 256 * FP * 2;   // 8.9 MB
    bf16* Wkk = (bf16*)w;             w += (size_t)512 * 256 * 2;
    bf16* Av = (bf16*)w;              w += (size_t)256 * 256 * 2;

    fft_fwd_kernel<<<NB * NC, 256, 0, stream>>>(x_in, Xf);
    xpack_kernel<<<(NB * FP * 256 + 255) / 256, 256, 0, stream>>>(Xf, Xb);
    wpack_kernel<<<512, 256, 0, stream>>>(W_K, W_V, Wkk, Av);
    kvgemm_kernel<<<NB * 17 * 4, 256, 0, stream>>>(Xb, Wkk, K12);
    vtgemm_kernel<<<NB * 17 * 2, 256, 0, stream>>>(Av, Xb, Vt);
    biasfix_kernel<<<NB, 128, 0, stream>>>(b_K, b_V, K12, Vt);
    energy_kernel<<<(NB * NF + 255) / 256, 256, 0, stream>>>(Xf, energy);
    median_kernel<<<NB * 9, 256, 0, stream>>>(energy, med);
    norm_kernel<<<(NB * NF + 255) / 256, 256, 0, stream>>>(energy, med, nrm);
    rankpart_kernel<<<65 * 17, 256, 0, stream>>>(nrm, rankpart);
    rankreduce_kernel<<<65, 256, 0, stream>>>(rankpart, nrm, qpar, vk);
    thresh_kernel<<<1, 64, 0, stream>>>(vk, qpar, thr);
    score_kernel<<<NB * 17 * 17, 256, 0, stream>>>(Xb, K12, S);
    softmax_kernel<<<NB * NF, 256, 0, stream>>>(S);
    context_kernel<<<NB * 33, 256, 0, stream>>>(S, Vt, Ctx);
    hifreq_kernel<<<(NB * NF * NC + 255) / 256, 256, 0, stream>>>(Ctx, Xf, nrm, thr, w_high);
    fft_inv_kernel<<<NB * NC, 256, 0, stream>>>(Ctx, out);
}

// Round 6
// 490.472 us; speedup vs baseline: 6.7990x; 1.1647x over previous
//
#include <hip/hip_runtime.h>
#include <math.h>

#define NB 8
#define NC 128
#define NT 4096
#define NF 2049
#define FP 2176   // padded F = 17*128
#define LDP 72    // LDS row pitch (64 + 8 bf16) -> 144 B, 2-way-max phases

typedef __bf16 bf16;
typedef __bf16 bf16x2 __attribute__((ext_vector_type(2)));
typedef __bf16 bf16x8 __attribute__((ext_vector_type(8)));
typedef float f32x4 __attribute__((ext_vector_type(4)));

// ---------------------------------------------------------------------------
// In-place radix-2 DIT FFT, length 4096, bit-reversed input. 256 threads.
// ---------------------------------------------------------------------------
__device__ __forceinline__ void fft4096(float2* buf) {
    for (int half = 1; half < NT; half <<= 1) {
        __syncthreads();
        const float fac = -(float)M_PI / (float)half;
        for (int t = threadIdx.x; t < NT / 2; t += 256) {
            int pos = t & (half - 1);
            int i = 2 * t - pos;
            int j = i + half;
            float sw, cw;
            __sincosf(fac * (float)pos, &sw, &cw);
            float2 u = buf[i], v = buf[j];
            float vr = v.x * cw - v.y * sw;
            float vi = v.x * sw + v.y * cw;
            buf[i] = make_float2(u.x + vr, u.y + vi);
            buf[j] = make_float2(u.x - vr, u.y - vi);
        }
    }
    __syncthreads();
}

// rfft -> Xc (B, C, F) float2, fully coalesced contiguous writes
__global__ __launch_bounds__(256) void fft_fwd_kernel(const float* __restrict__ x_in,
                                                      float2* __restrict__ Xc) {
    __shared__ float2 buf[NT];
    int bc = blockIdx.x;
    const float* xrow = x_in + (size_t)bc * NT;
    for (int i = threadIdx.x; i < NT; i += 256) {
        int r = __brev((unsigned)i) >> 20;
        buf[r] = make_float2(xrow[i], 0.0f);
    }
    fft4096(buf);
    const float inv = 1.0f / 64.0f;
    float2* orow = Xc + (size_t)bc * NF;
    for (int f = threadIdx.x; f < NF; f += 256) {
        float2 v = buf[f];
        orow[f] = make_float2(v.x * inv, v.y * inv);
    }
}

// Transpose Xc (B,C,F) -> Xf (B,F,2C) fp32 and Xb (B,FP,256) bf16 (pad zero)
__global__ __launch_bounds__(256) void xt_kernel(const float2* __restrict__ Xc,
                                                 float2* __restrict__ Xf2,
                                                 bf16* __restrict__ Xb) {
    __shared__ float2 tile[64][65];
    int blk = blockIdx.x;
    int b = blk / 68;
    int t2 = blk % 68;
    int c0 = (t2 / 34) * 64;
    int f0 = (t2 % 34) * 64;
    int t = threadIdx.x;
    int fl = t & 63, cc = t >> 6;
#pragma unroll
    for (int cb = 0; cb < 16; ++cb) {
        int cl = cb * 4 + cc;
        int f = f0 + fl;
        float2 v = make_float2(0.f, 0.f);
        if (f < NF) v = Xc[((size_t)b * NC + c0 + cl) * NF + f];
        tile[fl][cl] = v;
    }
    __syncthreads();
    int chl = t & 63, ww = t >> 6;
#pragma unroll
    for (int wb = 0; wb < 16; ++wb) {
        int fl2 = wb * 4 + ww;
        int f = f0 + fl2;
        float2 v = tile[fl2][chl];
        if (f < NF) Xf2[((size_t)b * NF + f) * 128 + c0 + chl] = v;
        bf16x2 p;
        p[0] = (bf16)v.x; p[1] = (bf16)v.y;
        *(bf16x2*)&Xb[((size_t)b * FP + f) * 256 + 2 * (c0 + chl)] = p;
    }
}

// ---------------------------------------------------------------------------
// Packed weight matrices (bf16):
//  Wkk (512 x 256): rows 0..255 -> K1 (Kr,-Ki interleaved), 256..511 -> K2
//  Av  (256 x 256): rows -> Vt (Vr,Vi interleaved)
// ---------------------------------------------------------------------------
__global__ __launch_bounds__(256) void wpack_kernel(const float* __restrict__ W_K,
                                                    const float* __restrict__ W_V,
                                                    bf16* __restrict__ Wkk,
                                                    bf16* __restrict__ Av) {
    int idx = blockIdx.x * 256 + threadIdx.x;
    if (idx < 512 * 256) {
        int n = idx >> 8, k = idx & 255;
        int c = k >> 1;
        float v = 0.f;
        if (n < 256) {
            int j = n >> 1;
            if (!(n & 1) && !(k & 1)) v = W_K[j * NC + c];
            else if ((n & 1) && (k & 1)) v = -W_K[j * NC + c];
        } else {
            int j = (n - 256) >> 1;
            if (!(n & 1) && (k & 1)) v = W_K[j * NC + c];
            else if ((n & 1) && !(k & 1)) v = W_K[j * NC + c];
        }
        Wkk[idx] = (bf16)v;
    }
    if (idx < 256 * 256) {
        int n = idx >> 8, k = idx & 255;
        int j = n >> 1, c = k >> 1;
        float v = 0.f;
        if (!(n & 1) && !(k & 1)) v = W_V[j * NC + c];
        else if ((n & 1) && (k & 1)) v = W_V[j * NC + c];
        Av[idx] = (bf16)v;
    }
}

// K12[(b*FP+g)*512 + n] = sum_k Xb[b,g,k] * Wkk[n,k]
__global__ __launch_bounds__(256, 2) void kvgemm_kernel(const bf16* __restrict__ Xb,
                                                        const bf16* __restrict__ Wkk,
                                                        bf16* __restrict__ K12) {
    __shared__ bf16 As[128][LDP];
    __shared__ bf16 Bs[128][LDP];
    int blk = blockIdx.x;
    int b = blk & 7;
    int t2 = blk >> 3;
    int g0 = (t2 >> 2) * 128;
    int n0 = (t2 & 3) * 128;
    int tid = threadIdx.x;
    int wave = tid >> 6, lane = tid & 63;
    int m = lane & 15, quad = lane >> 4;
    int row_off = (wave & 1) * 64, col_off = (wave >> 1) * 64;

    f32x4 acc[4][4] = {};
    const bf16* Abase = Xb + ((size_t)b * FP + g0) * 256;
    const bf16* Bbase = Wkk + (size_t)n0 * 256;
    int r0 = tid >> 3, c0 = (tid & 7) * 8;

    for (int kk = 0; kk < 256; kk += 64) {
        __syncthreads();
#pragma unroll
        for (int s = 0; s < 4; ++s) {
            int r = r0 + 32 * s;
            *(bf16x8*)&As[r][c0] = *(const bf16x8*)&Abase[(size_t)r * 256 + kk + c0];
            *(bf16x8*)&Bs[r][c0] = *(const bf16x8*)&Bbase[(size_t)r * 256 + kk + c0];
        }
        __syncthreads();
#pragma unroll
        for (int k2 = 0; k2 < 64; k2 += 32) {
            bf16x8 a[4], bb[4];
            int kq = k2 + quad * 8;
#pragma unroll
            for (int i = 0; i < 4; ++i) a[i] = *(const bf16x8*)&As[row_off + i * 16 + m][kq];
#pragma unroll
            for (int j = 0; j < 4; ++j) bb[j] = *(const bf16x8*)&Bs[col_off + j * 16 + m][kq];
#pragma unroll
            for (int i = 0; i < 4; ++i)
#pragma unroll
                for (int j = 0; j < 4; ++j)
                    acc[i][j] = __builtin_amdgcn_mfma_f32_16x16x32_bf16(a[i], bb[j], acc[i][j], 0, 0, 0);
        }
    }
#pragma unroll
    for (int i = 0; i < 4; ++i)
#pragma unroll
        for (int j = 0; j < 4; ++j)
#pragma unroll
            for (int r = 0; r < 4; ++r) {
                int row = g0 + row_off + i * 16 + quad * 4 + r;
                int col = n0 + col_off + j * 16 + m;
                K12[((size_t)b * FP + row) * 512 + col] = (bf16)acc[i][j][r];
            }
}

// Vt[(b*256+n)*FP + g] = sum_k Av[n,k] * Xb[b,g,k]
__global__ __launch_bounds__(256, 2) void vtgemm_kernel(const bf16* __restrict__ Av,
                                                        const bf16* __restrict__ Xb,
                                                        bf16* __restrict__ Vt) {
    __shared__ bf16 As[128][LDP];
    __shared__ bf16 Bs[128][LDP];
    int blk = blockIdx.x;
    int b = blk & 7;
    int t2 = blk >> 3;
    int g0 = (t2 >> 1) * 128;
    int n0 = (t2 & 1) * 128;
    int tid = threadIdx.x;
    int wave = tid >> 6, lane = tid & 63;
    int m = lane & 15, quad = lane >> 4;
    int row_off = (wave & 1) * 64, col_off = (wave >> 1) * 64;

    f32x4 acc[4][4] = {};
    const bf16* Abase = Av + (size_t)n0 * 256;
    const bf16* Bbase = Xb + ((size_t)b * FP + g0) * 256;
    int r0 = tid >> 3, c0 = (tid & 7) * 8;

    for (int kk = 0; kk < 256; kk += 64) {
        __syncthreads();
#pragma unroll
        for (int s = 0; s < 4; ++s) {
            int r = r0 + 32 * s;
            *(bf16x8*)&As[r][c0] = *(const bf16x8*)&Abase[(size_t)r * 256 + kk + c0];
            *(bf16x8*)&Bs[r][c0] = *(const bf16x8*)&Bbase[(size_t)r * 256 + kk + c0];
        }
        __syncthreads();
#pragma unroll
        for (int k2 = 0; k2 < 64; k2 += 32) {
            bf16x8 a[4], bb[4];
            int kq = k2 + quad * 8;
#pragma unroll
            for (int i = 0; i < 4; ++i) a[i] = *(const bf16x8*)&As[row_off + i * 16 + m][kq];
#pragma unroll
            for (int j = 0; j < 4; ++j) bb[j] = *(const bf16x8*)&Bs[col_off + j * 16 + m][kq];
#pragma unroll
            for (int i = 0; i < 4; ++i)
#pragma unroll
                for (int j = 0; j < 4; ++j)
                    acc[i][j] = __builtin_amdgcn_mfma_f32_16x16x32_bf16(a[i], bb[j], acc[i][j], 0, 0, 0);
        }
    }
#pragma unroll
    for (int i = 0; i < 4; ++i)
#pragma unroll
        for (int j = 0; j < 4; ++j)
#pragma unroll
            for (int r = 0; r < 4; ++r) {
                int row = n0 + row_off + i * 16 + quad * 4 + r;
                int col = g0 + col_off + j * 16 + m;
                Vt[((size_t)b * 256 + row) * FP + col] = (bf16)acc[i][j][r];
            }
}

// DC-bin bias: rfft(const b, ortho) = sqrt(N)*b at f=0 only (re part)
__global__ __launch_bounds__(128) void biasfix_kernel(const float* __restrict__ b_K,
                                                      const float* __restrict__ b_V,
                                                      bf16* __restrict__ K12,
                                                      bf16* __restrict__ Vt) {
    int b = blockIdx.x;
    int j = threadIdx.x;
    float bk = 64.0f * b_K[j], bv = 64.0f * b_V[j];
    size_t o = (size_t)b * FP * 512;
    K12[o + 2 * j] = (bf16)((float)K12[o + 2 * j] + bk);
    K12[o + 256 + 2 * j + 1] = (bf16)((float)K12[o + 256 + 2 * j + 1] + bk);
    size_t ov = ((size_t)b * 256 + 2 * j) * FP;
    Vt[ov] = (bf16)((float)Vt[ov] + bv);
}

__global__ __launch_bounds__(256) void energy_kernel(const float* __restrict__ Xf,
                                                     float* __restrict__ energy) {
    int idx = blockIdx.x * 256 + threadIdx.x;
    if (idx >= NB * NF) return;
    const float4* row = (const float4*)(Xf + (size_t)idx * 2 * NC);
    float e = 0.f;
    for (int i = 0; i < 64; ++i) {
        float4 v = row[i];
        e += v.x * v.x + v.y * v.y + v.z * v.z + v.w * v.w;
    }
    energy[idx] = e;
}

// per-batch median: batch x 9 chunk blocks, float4 LDS rank loop
__global__ __launch_bounds__(256) void median_kernel(const float* __restrict__ energy,
                                                     float* __restrict__ med) {
    int blk = blockIdx.x;
    int b = blk / 9, chunk = blk % 9;
    __shared__ __align__(16) float e[2052];
    for (int i = threadIdx.x; i < 2052; i += 256)
        e[i] = (i < NF) ? energy[b * NF + i] : INFINITY;
    __syncthreads();
    int i = chunk * 256 + threadIdx.x;
    float ei = (i < NF) ? e[i] : 0.f;
    int rank = 0;
#pragma unroll 4
    for (int j4 = 0; j4 < 513; ++j4) {
        float4 v = ((const float4*)e)[j4];
        int j = j4 * 4;
        rank += (v.x < ei) || (v.x == ei && j + 0 < i);
        rank += (v.y < ei) || (v.y == ei && j + 1 < i);
        rank += (v.z < ei) || (v.z == ei && j + 2 < i);
        rank += (v.w < ei) || (v.w == ei && j + 3 < i);
    }
    if (i < NF && rank == 1024) med[b] = ei;
}

__global__ __launch_bounds__(256) void norm_kernel(const float* __restrict__ energy,
                                                   const float* __restrict__ med,
                                                   float* __restrict__ nrm) {
    int idx = blockIdx.x * 256 + threadIdx.x;
    if (idx >= NB * NF) return;
    int b = idx / NF;
    nrm[idx] = energy[idx] / (med[b] + 1e-6f);
}

// Global quantile: 2-D distributed rank selection.
__global__ __launch_bounds__(256) void rankpart_kernel(const float* __restrict__ nrm,
                                                       int* __restrict__ rankpart) {
    const int n = NB * NF;
    int cb = blockIdx.x / 17;
    int chunk = blockIdx.x % 17;
    __shared__ __align__(16) float cdata[1024];
    int base = chunk * 1024;
    for (int t = threadIdx.x; t < 1024; t += 256)
        cdata[t] = (base + t < n) ? nrm[base + t] : INFINITY;
    __syncthreads();
    int i = cb * 256 + threadIdx.x;
    if (i >= n) return;
    float ei = nrm[i];
    int rank = 0;
#pragma unroll 8
    for (int t4 = 0; t4 < 256; ++t4) {
        float4 v = ((const float4*)cdata)[t4];
        int j = base + t4 * 4;
        rank += (v.x < ei) || (v.x == ei && j + 0 < i);
        rank += (v.y < ei) || (v.y == ei && j + 1 < i);
        rank += (v.z < ei) || (v.z == ei && j + 2 < i);
        rank += (v.w < ei) || (v.w == ei && j + 3 < i);
    }
    rankpart[(size_t)i * 17 + chunk] = rank;
}

__global__ __launch_bounds__(256) void rankreduce_kernel(const int* __restrict__ rankpart,
                                                         const float* __restrict__ nrm,
                                                         const float* __restrict__ q,
                                                         float* __restrict__ vk) {
    const int n = NB * NF;
    int i = blockIdx.x * 256 + threadIdx.x;
    if (i >= n) return;
    int rank = 0;
    const int* rp = rankpart + (size_t)i * 17;
#pragma unroll
    for (int c = 0; c < 17; ++c) rank += rp[c];
    double pos = (double)q[0] * (double)(n - 1);
    int k0 = (int)floor(pos);
    int k1 = min(k0 + 1, n - 1);
    if (rank == k0) vk[0] = nrm[i];
    if (rank == k1) vk[1] = nrm[i];
}

__global__ void thresh_kernel(const float* __restrict__ vk,
                              const float* __restrict__ q,
                              float* __restrict__ thr) {
    if (threadIdx.x == 0 && blockIdx.x == 0) {
        const int n = NB * NF;
        double pos = (double)q[0] * (double)(n - 1);
        double k0 = floor(pos);
        double frac = pos - k0;
        thr[0] = (float)((double)vk[0] + ((double)vk[1] - (double)vk[0]) * frac);
    }
}

// ---------------------------------------------------------------------------
// Scores via MFMA, XCD-swizzled (b = blk&7), LDS-staged coalesced C-write.
// ---------------------------------------------------------------------------
__global__ __launch_bounds__(256, 2) void score_kernel(const bf16* __restrict__ Xb,
                                                       const bf16* __restrict__ K12,
                                                       bf16* __restrict__ S) {
    __shared__ __align__(16) char smem[55296];
    bf16 (*As)[LDP]  = (bf16(*)[LDP])smem;
    bf16 (*B1s)[LDP] = (bf16(*)[LDP])(smem + 18432);
    bf16 (*B2s)[LDP] = (bf16(*)[LDP])(smem + 36864);
    int blk = blockIdx.x;
    int b = blk & 7;
    int t2 = blk >> 3;
    int f0 = (t2 / 17) * 128;
    int g0 = (t2 % 17) * 128;
    int tid = threadIdx.x;
    int wave = tid >> 6, lane = tid & 63;
    int m = lane & 15, quad = lane >> 4;
    int row_off = (wave & 1) * 64, col_off = (wave >> 1) * 64;

    f32x4 accRe[4][4] = {};
    f32x4 accIm[4][4] = {};
    const bf16* Abase = Xb + ((size_t)b * FP + f0) * 256;
    const bf16* Kbase = K12 + ((size_t)b * FP + g0) * 512;
    int r0 = tid >> 3, c0 = (tid & 7) * 8;

    for (int kk = 0; kk < 256; kk += 64) {
        __syncthreads();
#pragma unroll
        for (int s = 0; s < 4; ++s) {
            int r = r0 + 32 * s;
            *(bf16x8*)&As[r][c0] = *(const bf16x8*)&Abase[(size_t)r * 256 + kk + c0];
            *(bf16x8*)&B1s[r][c0] = *(const bf16x8*)&Kbase[(size_t)r * 512 + kk + c0];
            *(bf16x8*)&B2s[r][c0] = *(const bf16x8*)&Kbase[(size_t)r * 512 + 256 + kk + c0];
        }
        __syncthreads();
#pragma unroll
        for (int k2 = 0; k2 < 64; k2 += 32) {
            bf16x8 a[4], b1[4], b2[4];
            int kq = k2 + quad * 8;
#pragma unroll
            for (int i = 0; i < 4; ++i) a[i] = *(const bf16x8*)&As[row_off + i * 16 + m][kq];
#pragma unroll
            for (int j = 0; j < 4; ++j) b1[j] = *(const bf16x8*)&B1s[col_off + j * 16 + m][kq];
#pragma unroll
            for (int j = 0; j < 4; ++j) b2[j] = *(const bf16x8*)&B2s[col_off + j * 16 + m][kq];
#pragma unroll
            for (int i = 0; i < 4; ++i)
#pragma unroll
                for (int j = 0; j < 4; ++j) {
                    accRe[i][j] = __builtin_amdgcn_mfma_f32_16x16x32_bf16(a[i], b1[j], accRe[i][j], 0, 0, 0);
                    accIm[i][j] = __builtin_amdgcn_mfma_f32_16x16x32_bf16(a[i], b2[j], accIm[i][j], 0, 0, 0);
                }
        }
    }
    const float SCALE = 0.08838834764831845f;  // 1/sqrt(128)
    __syncthreads();
    bf16 (*Cs)[136] = (bf16(*)[136])smem;  // 128 x 136 bf16 = 34816 B
#pragma unroll
    for (int i = 0; i < 4; ++i)
#pragma unroll
        for (int j = 0; j < 4; ++j)
#pragma unroll
            for (int r = 0; r < 4; ++r) {
                float re = accRe[i][j][r], im = accIm[i][j][r];
                Cs[row_off + i * 16 + quad * 4 + r][col_off + j * 16 + m] =
                    (bf16)(sqrtf(re * re + im * im) * SCALE);
            }
    __syncthreads();
    bf16* Sb = S + (size_t)b * FP * FP;
    int row = tid >> 1, half = tid & 1;
    const bf16* src = &Cs[row][half * 64];
    bf16* dst = Sb + (size_t)(f0 + row) * FP + g0 + half * 64;
#pragma unroll
    for (int u = 0; u < 8; ++u)
        *(bf16x8*)&dst[u * 8] = *(const bf16x8*)&src[u * 8];
}

// single-read row softmax in place (bf16), zero pad cols
__global__ __launch_bounds__(256) void softmax_kernel(bf16* __restrict__ S) {
    int bf = blockIdx.x;
    int b = bf / NF, f = bf % NF;
    bf16* row = S + ((size_t)b * FP + f) * FP;
    int t = threadIdx.x;
    __shared__ float red[256];
    bf16x8 raw = *(const bf16x8*)&row[t * 8];  // covers g = 0..2047
    float tail = (t == 0) ? (float)row[2048] : -1e30f;
    float v[8];
    float mx = tail;
#pragma unroll
    for (int u = 0; u < 8; ++u) { v[u] = (float)raw[u]; mx = fmaxf(mx, v[u]); }
    red[t] = mx;
    __syncthreads();
    for (int s = 128; s > 0; s >>= 1) {
        if (t < s) red[t] = fmaxf(red[t], red[t + s]);
        __syncthreads();
    }
    float mval = red[0];
    __syncthreads();
    float sum = 0.f;
#pragma unroll
    for (int u = 0; u < 8; ++u) { v[u] = __expf(v[u] - mval); sum += v[u]; }
    float tex = 0.f;
    if (t == 0) { tex = __expf(tail - mval); sum += tex; }
    red[t] = sum;
    __syncthreads();
    for (int s = 128; s > 0; s >>= 1) {
        if (t < s) red[t] += red[t + s];
        __syncthreads();
    }
    float inv = 1.f / red[0];
    bf16x8 outv;
#pragma unroll
    for (int u = 0; u < 8; ++u) outv[u] = (bf16)(v[u] * inv);
    *(bf16x8*)&row[t * 8] = outv;
    if (t == 0) row[2048] = (bf16)(tex * inv);
    if (t < FP - NF) row[NF + t] = (bf16)0.f;  // zero 127 pad cols
}

// ---------------------------------------------------------------------------
// Context via MFMA: Ctx[f,j] = sum_g P[f,g] Vt[j,g]. XCD-swizzled.
// ---------------------------------------------------------------------------
__global__ __launch_bounds__(256, 2) void context_kernel(const bf16* __restrict__ P,
                                                         const bf16* __restrict__ Vt,
                                                         float* __restrict__ Ctx) {
    __shared__ bf16 Ps[64][LDP];
    __shared__ bf16 Vs[256][LDP];
    int blk = blockIdx.x;
    int b = blk & 7;
    int f0 = (blk >> 3) * 64;
    int tid = threadIdx.x;
    int wave = tid >> 6, lane = tid & 63;
    int m = lane & 15, quad = lane >> 4;
    int col_off = wave * 64;

    f32x4 acc[4][4] = {};
    const bf16* Pbase = P + ((size_t)b * FP + f0) * FP;
    const bf16* Vbase = Vt + (size_t)b * 256 * FP;
    int r0 = tid >> 3, c0 = (tid & 7) * 8;

    for (int kk = 0; kk < FP; kk += 64) {
        __syncthreads();
#pragma unroll
        for (int s = 0; s < 2; ++s) {
            int r = r0 + 32 * s;
            *(bf16x8*)&Ps[r][c0] = *(const bf16x8*)&Pbase[(size_t)r * FP + kk + c0];
        }
#pragma unroll
        for (int s = 0; s < 8; ++s) {
            int r = r0 + 32 * s;
            *(bf16x8*)&Vs[r][c0] = *(const bf16x8*)&Vbase[(size_t)r * FP + kk + c0];
        }
        __syncthreads();
#pragma unroll
        for (int k2 = 0; k2 < 64; k2 += 32) {
            bf16x8 a[4], bb[4];
            int kq = k2 + quad * 8;
#pragma unroll
            for (int i = 0; i < 4; ++i) a[i] = *(const bf16x8*)&Ps[i * 16 + m][kq];
#pragma unroll
            for (int j = 0; j < 4; ++j) bb[j] = *(const bf16x8*)&Vs[col_off + j * 16 + m][kq];
#pragma unroll
            for (int i = 0; i < 4; ++i)
#pragma unroll
                for (int j = 0; j < 4; ++j)
                    acc[i][j] = __builtin_amdgcn_mfma_f32_16x16x32_bf16(a[i], bb[j], acc[i][j], 0, 0, 0);
        }
    }
#pragma unroll
    for (int i = 0; i < 4; ++i)
#pragma unroll
        for (int j = 0; j < 4; ++j)
#pragma unroll
            for (int r = 0; r < 4; ++r) {
                int row = f0 + i * 16 + quad * 4 + r;
                int col = col_off + j * 16 + m;
                if (row < NF) Ctx[((size_t)b * NF + row) * 256 + col] = acc[i][j][r];
            }
}

// Fused hifreq + transpose: Ctxt[b, ch, f] = Ctx[b,f,ch] + mask*(X*w_hi)
__global__ __launch_bounds__(256) void ctxt_kernel(const float2* __restrict__ Ctx2,
                                                   const float2* __restrict__ Xf2,
                                                   const float* __restrict__ nrm,
                                                   const float* __restrict__ thr,
                                                   const float* __restrict__ w_high,
                                                   float* __restrict__ Ctxt) {
    __shared__ float2 tile[64][33];
    int blk = blockIdx.x;
    int b = blk / 132;
    int t2 = blk % 132;
    int cp0 = (t2 / 33) * 32;
    int f0 = (t2 % 33) * 64;
    int t = threadIdx.x;
    float thrv = thr[0];
    int cpl = t & 31, rr = t >> 5;
#pragma unroll
    for (int rb = 0; rb < 8; ++rb) {
        int fl = rb * 8 + rr;
        int f = f0 + fl;
        float2 v = make_float2(0.f, 0.f);
        if (f < NF) {
            size_t idx = ((size_t)b * NF + f) * 128 + cp0 + cpl;
            v = Ctx2[idx];
            if (nrm[b * NF + f] > thrv) {
                float2 x = Xf2[idx];
                int c = cp0 + cpl;
                float wr = w_high[2 * c], wi = w_high[2 * c + 1];
                v.x += x.x * wr - x.y * wi;
                v.y += x.x * wi + x.y * wr;
            }
        }
        tile[fl][cpl] = v;
    }
    __syncthreads();
    int fl = t & 63, ww = t >> 6;
#pragma unroll
    for (int wb = 0; wb < 16; ++wb) {
        int chl = wb * 4 + ww;
        int f = f0 + fl;
        if (f < NF) {
            float2 v = tile[fl][chl >> 1];
            Ctxt[((size_t)b * 256 + 2 * cp0 + chl) * NF + f] = (chl & 1) ? v.y : v.x;
        }
    }
}

// irfft (ortho) reading contiguous Ctxt rows
__global__ __launch_bounds__(256) void fft_inv_kernel(const float* __restrict__ Ctxt,
                                                      float* __restrict__ out) {
    __shared__ float2 buf[NT];
    int bc = blockIdx.x, b = bc >> 7, c = bc & 127;
    const float* base = Ctxt + ((size_t)b * 256 + 2 * c) * NF;
    const float* basei = base + NF;
    for (int f = threadIdx.x; f < NT; f += 256) {
        float re, im;
        if (f <= NT / 2) {
            re = base[f];
            im = -basei[f];
        } else {
            int g = NT - f;
            re = base[g];
            im = basei[g];
        }
        int r = __brev((unsigned)f) >> 20;
        buf[r] = make_float2(re, im);
    }
    fft4096(buf);
    float* orow = out + (size_t)bc * NT;
    const float inv = 1.0f / 64.0f;
    for (int n = threadIdx.x; n < NT; n += 256) orow[n] = buf[n].x * inv;
}

extern "C" void kernel_launch(void* const* d_in, const int* in_sizes, int n_in,
                              void* d_out, int out_size, void* d_ws, size_t ws_size,
                              hipStream_t stream) {
    const float* x_in = (const float*)d_in[0];
    const float* W_K = (const float*)d_in[1];
    const float* b_K = (const float*)d_in[2];
    const float* W_V = (const float*)d_in[3];
    const float* b_V = (const float*)d_in[4];
    const float* w_high = (const float*)d_in[5];
    const float* qpar = (const float*)d_in[6];
    float* out = (float*)d_out;

    char* w = (char*)d_ws;
    const size_t SPECB = (size_t)NB * NF * 256 * 4;       // 16.8 MB
    float* Xf = (float*)w;            w += SPECB;
    float* Ctx = (float*)w;           w += SPECB;
    float* energy = (float*)w;        w += (size_t)NB * NF * 4;
    float* med = (float*)w;           w += 64;
    float* nrm = (float*)w;           w += (size_t)NB * NF * 4;
    float* vk = (float*)w;            w += 64;
    float* thr = (float*)w;           w += 64;
    w = (char*)(((uintptr_t)w + 255) & ~(uintptr_t)255);
    int* rankpart = (int*)w;          w += (size_t)16640 * 17 * 4;      // 1.1 MB
    w = (char*)(((uintptr_t)w + 255) & ~(uintptr_t)255);
    bf16* S = (bf16*)w;               w += (size_t)NB * FP * FP * 2;    // 75.8 MB
    bf16* Xb = (bf16*)w;              w += (size_t)NB * FP * 256 * 2;   // 8.9 MB
    bf16* K12 = (bf16*)w;             w += (size_t)NB * FP * 512 * 2;   // 17.8 MB
    bf16* Vt = (bf16*)w;              w += (size_t)NB * 256 * FP * 2;   // 8.9 MB
    bf16* Wkk = (bf16*)w;             w += (size_t)512 * 256 * 2;
    bf16* Av = (bf16*)w;              w += (size_t)256 * 256 * 2;
    // Aliases (lifetimes disjoint):
    float2* Xc = (float2*)S;      // 16.8 MB, used only fft_fwd -> xt (S written later)
    float* Ctxt = (float*)Xb;     // 16.8 MB over Xb+K12 (dead after score)

    fft_fwd_kernel<<<NB * NC, 256, 0, stream>>>(x_in, Xc);
    xt_kernel<<<NB * 2 * 34, 256, 0, stream>>>(Xc, (float2*)Xf, Xb);
    wpack_kernel<<<512, 256, 0, stream>>>(W_K, W_V, Wkk, Av);
    kvgemm_kernel<<<NB * 17 * 4, 256, 0, stream>>>(Xb, Wkk, K12);
    vtgemm_kernel<<<NB * 17 * 2, 256, 0, stream>>>(Av, Xb, Vt);
    biasfix_kernel<<<NB, 128, 0, stream>>>(b_K, b_V, K12, Vt);
    energy_kernel<<<(NB * NF + 255) / 256, 256, 0, stream>>>(Xf, energy);
    median_kernel<<<NB * 9, 256, 0, stream>>>(energy, med);
    norm_kernel<<<(NB * NF + 255) / 256, 256, 0, stream>>>(energy, med, nrm);
    rankpart_kernel<<<65 * 17, 256, 0, stream>>>(nrm, rankpart);
    rankreduce_kernel<<<65, 256, 0, stream>>>(rankpart, nrm, qpar, vk);
    thresh_kernel<<<1, 64, 0, stream>>>(vk, qpar, thr);
    score_kernel<<<NB * 17 * 17, 256, 0, stream>>>(Xb, K12, S);
    softmax_kernel<<<NB * NF, 256, 0, stream>>>(S);
    context_kernel<<<NB * 33, 256, 0, stream>>>(S, Vt, Ctx);
    ctxt_kernel<<<NB * 4 * 33, 256, 0, stream>>>((const float2*)Ctx, (const float2*)Xf,
                                                 nrm, thr, w_high, Ctxt);
    fft_inv_kernel<<<NB * NC, 256, 0, stream>>>(Ctxt, out);
}

// Round 7
// 433.800 us; speedup vs baseline: 7.6872x; 1.1306x over previous
//
#include <hip/hip_runtime.h>
#include <math.h>

#define NB 8
#define NC 128
#define NT 4096
#define NF 2049
#define FP 2176   // padded F = 17*128
#define LDP 72    // LDS row pitch for non-async GEMMs (144 B)

typedef __bf16 bf16;
typedef __bf16 bf16x2 __attribute__((ext_vector_type(2)));
typedef __bf16 bf16x8 __attribute__((ext_vector_type(8)));
typedef float f32x4 __attribute__((ext_vector_type(4)));
typedef unsigned int uint32x4 __attribute__((ext_vector_type(4)));

// async global->LDS, 16 B per lane; lds dest must be wave-uniform base
__device__ __forceinline__ void async16(const bf16* g, bf16* l) {
    __builtin_amdgcn_global_load_lds(
        (const __attribute__((address_space(1))) void*)g,
        (__attribute__((address_space(3))) void*)l, 16, 0, 0);
}

// (Kr,-Ki) interleaved fragment -> (Ki,Kr): per dword swap halves, negate low
__device__ __forceinline__ bf16x8 derive_b2(bf16x8 v) {
    uint32x4 u = __builtin_bit_cast(uint32x4, v);
#pragma unroll
    for (int i = 0; i < 4; ++i)
        u[i] = (((u[i] >> 16) | (u[i] << 16)) ^ 0x00008000u);
    return __builtin_bit_cast(bf16x8, u);
}

// ---------------------------------------------------------------------------
// In-place radix-2 DIT FFT, length 4096, bit-reversed input. 256 threads.
// ---------------------------------------------------------------------------
__device__ __forceinline__ void fft4096(float2* buf) {
    for (int half = 1; half < NT; half <<= 1) {
        __syncthreads();
        const float fac = -(float)M_PI / (float)half;
        for (int t = threadIdx.x; t < NT / 2; t += 256) {
            int pos = t & (half - 1);
            int i = 2 * t - pos;
            int j = i + half;
            float sw, cw;
            __sincosf(fac * (float)pos, &sw, &cw);
            float2 u = buf[i], v = buf[j];
            float vr = v.x * cw - v.y * sw;
            float vi = v.x * sw + v.y * cw;
            buf[i] = make_float2(u.x + vr, u.y + vi);
            buf[j] = make_float2(u.x - vr, u.y - vi);
        }
    }
    __syncthreads();
}

// rfft -> Xc (B, C, F) float2, fully coalesced contiguous writes
__global__ __launch_bounds__(256) void fft_fwd_kernel(const float* __restrict__ x_in,
                                                      float2* __restrict__ Xc) {
    __shared__ float2 buf[NT];
    int bc = blockIdx.x;
    const float* xrow = x_in + (size_t)bc * NT;
    for (int i = threadIdx.x; i < NT; i += 256) {
        int r = __brev((unsigned)i) >> 20;
        buf[r] = make_float2(xrow[i], 0.0f);
    }
    fft4096(buf);
    const float inv = 1.0f / 64.0f;
    float2* orow = Xc + (size_t)bc * NF;
    for (int f = threadIdx.x; f < NF; f += 256) {
        float2 v = buf[f];
        orow[f] = make_float2(v.x * inv, v.y * inv);
    }
}

// Transpose Xc (B,C,F) -> Xf (B,F,2C) fp32 and Xb (B,FP,256) bf16 (pad zero)
__global__ __launch_bounds__(256) void xt_kernel(const float2* __restrict__ Xc,
                                                 float2* __restrict__ Xf2,
                                                 bf16* __restrict__ Xb) {
    __shared__ float2 tile[64][65];
    int blk = blockIdx.x;
    int b = blk / 68;
    int t2 = blk % 68;
    int c0 = (t2 / 34) * 64;
    int f0 = (t2 % 34) * 64;
    int t = threadIdx.x;
    int fl = t & 63, cc = t >> 6;
#pragma unroll
    for (int cb = 0; cb < 16; ++cb) {
        int cl = cb * 4 + cc;
        int f = f0 + fl;
        float2 v = make_float2(0.f, 0.f);
        if (f < NF) v = Xc[((size_t)b * NC + c0 + cl) * NF + f];
        tile[fl][cl] = v;
    }
    __syncthreads();
    int chl = t & 63, ww = t >> 6;
#pragma unroll
    for (int wb = 0; wb < 16; ++wb) {
        int fl2 = wb * 4 + ww;
        int f = f0 + fl2;
        float2 v = tile[fl2][chl];
        if (f < NF) Xf2[((size_t)b * NF + f) * 128 + c0 + chl] = v;
        bf16x2 p;
        p[0] = (bf16)v.x; p[1] = (bf16)v.y;
        *(bf16x2*)&Xb[((size_t)b * FP + f) * 256 + 2 * (c0 + chl)] = p;
    }
}

// ---------------------------------------------------------------------------
// Packed weight matrices (bf16):
//  Wk1 (256 x 256): rows -> K1 (Kr,-Ki interleaved)   [K2 derived in-register]
//  Av  (256 x 256): rows -> Vt (Vr,Vi interleaved)
// ---------------------------------------------------------------------------
__global__ __launch_bounds__(256) void wpack_kernel(const float* __restrict__ W_K,
                                                    const float* __restrict__ W_V,
                                                    bf16* __restrict__ Wk1,
                                                    bf16* __restrict__ Av) {
    int idx = blockIdx.x * 256 + threadIdx.x;
    if (idx < 256 * 256) {
        int n = idx >> 8, k = idx & 255;
        int c = k >> 1;
        int j = n >> 1;
        float v = 0.f;
        if (!(n & 1) && !(k & 1)) v = W_K[j * NC + c];
        else if ((n & 1) && (k & 1)) v = -W_K[j * NC + c];
        Wk1[idx] = (bf16)v;
        float v2 = 0.f;
        if (!(n & 1) && !(k & 1)) v2 = W_V[j * NC + c];
        else if ((n & 1) && (k & 1)) v2 = W_V[j * NC + c];
        Av[idx] = (bf16)v2;
    }
}

// K1[(b*FP+g)*256 + n] = sum_k Xb[b,g,k] * Wk1[n,k]
__global__ __launch_bounds__(256, 2) void kvgemm_kernel(const bf16* __restrict__ Xb,
                                                        const bf16* __restrict__ Wk1,
                                                        bf16* __restrict__ K1) {
    __shared__ bf16 As[128][LDP];
    __shared__ bf16 Bs[128][LDP];
    int blk = blockIdx.x;
    int b = blk & 7;
    int t2 = blk >> 3;
    int g0 = (t2 >> 1) * 128;
    int n0 = (t2 & 1) * 128;
    int tid = threadIdx.x;
    int wave = tid >> 6, lane = tid & 63;
    int m = lane & 15, quad = lane >> 4;
    int row_off = (wave & 1) * 64, col_off = (wave >> 1) * 64;

    f32x4 acc[4][4] = {};
    const bf16* Abase = Xb + ((size_t)b * FP + g0) * 256;
    const bf16* Bbase = Wk1 + (size_t)n0 * 256;
    int r0 = tid >> 3, c0 = (tid & 7) * 8;

    for (int kk = 0; kk < 256; kk += 64) {
        __syncthreads();
#pragma unroll
        for (int s = 0; s < 4; ++s) {
            int r = r0 + 32 * s;
            *(bf16x8*)&As[r][c0] = *(const bf16x8*)&Abase[(size_t)r * 256 + kk + c0];
            *(bf16x8*)&Bs[r][c0] = *(const bf16x8*)&Bbase[(size_t)r * 256 + kk + c0];
        }
        __syncthreads();
#pragma unroll
        for (int k2 = 0; k2 < 64; k2 += 32) {
            bf16x8 a[4], bb[4];
            int kq = k2 + quad * 8;
#pragma unroll
            for (int i = 0; i < 4; ++i) a[i] = *(const bf16x8*)&As[row_off + i * 16 + m][kq];
#pragma unroll
            for (int j = 0; j < 4; ++j) bb[j] = *(const bf16x8*)&Bs[col_off + j * 16 + m][kq];
#pragma unroll
            for (int i = 0; i < 4; ++i)
#pragma unroll
                for (int j = 0; j < 4; ++j)
                    acc[i][j] = __builtin_amdgcn_mfma_f32_16x16x32_bf16(a[i], bb[j], acc[i][j], 0, 0, 0);
        }
    }
#pragma unroll
    for (int i = 0; i < 4; ++i)
#pragma unroll
        for (int j = 0; j < 4; ++j)
#pragma unroll
            for (int r = 0; r < 4; ++r) {
                int row = g0 + row_off + i * 16 + quad * 4 + r;
                int col = n0 + col_off + j * 16 + m;
                K1[((size_t)b * FP + row) * 256 + col] = (bf16)acc[i][j][r];
            }
}

// Vt[(b*256+n)*FP + g] = sum_k Av[n,k] * Xb[b,g,k]
__global__ __launch_bounds__(256, 2) void vtgemm_kernel(const bf16* __restrict__ Av,
                                                        const bf16* __restrict__ Xb,
                                                        bf16* __restrict__ Vt) {
    __shared__ bf16 As[128][LDP];
    __shared__ bf16 Bs[128][LDP];
    int blk = blockIdx.x;
    int b = blk & 7;
    int t2 = blk >> 3;
    int g0 = (t2 >> 1) * 128;
    int n0 = (t2 & 1) * 128;
    int tid = threadIdx.x;
    int wave = tid >> 6, lane = tid & 63;
    int m = lane & 15, quad = lane >> 4;
    int row_off = (wave & 1) * 64, col_off = (wave >> 1) * 64;

    f32x4 acc[4][4] = {};
    const bf16* Abase = Av + (size_t)n0 * 256;
    const bf16* Bbase = Xb + ((size_t)b * FP + g0) * 256;
    int r0 = tid >> 3, c0 = (tid & 7) * 8;

    for (int kk = 0; kk < 256; kk += 64) {
        __syncthreads();
#pragma unroll
        for (int s = 0; s < 4; ++s) {
            int r = r0 + 32 * s;
            *(bf16x8*)&As[r][c0] = *(const bf16x8*)&Abase[(size_t)r * 256 + kk + c0];
            *(bf16x8*)&Bs[r][c0] = *(const bf16x8*)&Bbase[(size_t)r * 256 + kk + c0];
        }
        __syncthreads();
#pragma unroll
        for (int k2 = 0; k2 < 64; k2 += 32) {
            bf16x8 a[4], bb[4];
            int kq = k2 + quad * 8;
#pragma unroll
            for (int i = 0; i < 4; ++i) a[i] = *(const bf16x8*)&As[row_off + i * 16 + m][kq];
#pragma unroll
            for (int j = 0; j < 4; ++j) bb[j] = *(const bf16x8*)&Bs[col_off + j * 16 + m][kq];
#pragma unroll
            for (int i = 0; i < 4; ++i)
#pragma unroll
                for (int j = 0; j < 4; ++j)
                    acc[i][j] = __builtin_amdgcn_mfma_f32_16x16x32_bf16(a[i], bb[j], acc[i][j], 0, 0, 0);
        }
    }
#pragma unroll
    for (int i = 0; i < 4; ++i)
#pragma unroll
        for (int j = 0; j < 4; ++j)
#pragma unroll
            for (int r = 0; r < 4; ++r) {
                int row = n0 + row_off + i * 16 + quad * 4 + r;
                int col = g0 + col_off + j * 16 + m;
                Vt[((size_t)b * 256 + row) * FP + col] = (bf16)acc[i][j][r];
            }
}

// DC-bin bias: rfft(const b, ortho) = sqrt(N)*b at f=0 only (re part)
__global__ __launch_bounds__(128) void biasfix_kernel(const float* __restrict__ b_K,
                                                      const float* __restrict__ b_V,
                                                      bf16* __restrict__ K1,
                                                      bf16* __restrict__ Vt) {
    int b = blockIdx.x;
    int j = threadIdx.x;
    float bk = 64.0f * b_K[j], bv = 64.0f * b_V[j];
    size_t o = (size_t)b * FP * 256;
    K1[o + 2 * j] = (bf16)((float)K1[o + 2 * j] + bk);
    size_t ov = ((size_t)b * 256 + 2 * j) * FP;
    Vt[ov] = (bf16)((float)Vt[ov] + bv);
}

__global__ __launch_bounds__(256) void energy_kernel(const float* __restrict__ Xf,
                                                     float* __restrict__ energy) {
    int idx = blockIdx.x * 256 + threadIdx.x;
    if (idx >= NB * NF) return;
    const float4* row = (const float4*)(Xf + (size_t)idx * 2 * NC);
    float e = 0.f;
    for (int i = 0; i < 64; ++i) {
        float4 v = row[i];
        e += v.x * v.x + v.y * v.y + v.z * v.z + v.w * v.w;
    }
    energy[idx] = e;
}

// per-batch median: batch x 9 chunk blocks, float4 LDS rank loop
__global__ __launch_bounds__(256) void median_kernel(const float* __restrict__ energy,
                                                     float* __restrict__ med) {
    int blk = blockIdx.x;
    int b = blk / 9, chunk = blk % 9;
    __shared__ __align__(16) float e[2052];
    for (int i = threadIdx.x; i < 2052; i += 256)
        e[i] = (i < NF) ? energy[b * NF + i] : INFINITY;
    __syncthreads();
    int i = chunk * 256 + threadIdx.x;
    float ei = (i < NF) ? e[i] : 0.f;
    int rank = 0;
#pragma unroll 4
    for (int j4 = 0; j4 < 513; ++j4) {
        float4 v = ((const float4*)e)[j4];
        int j = j4 * 4;
        rank += (v.x < ei) || (v.x == ei && j + 0 < i);
        rank += (v.y < ei) || (v.y == ei && j + 1 < i);
        rank += (v.z < ei) || (v.z == ei && j + 2 < i);
        rank += (v.w < ei) || (v.w == ei && j + 3 < i);
    }
    if (i < NF && rank == 1024) med[b] = ei;
}

__global__ __launch_bounds__(256) void norm_kernel(const float* __restrict__ energy,
                                                   const float* __restrict__ med,
                                                   float* __restrict__ nrm) {
    int idx = blockIdx.x * 256 + threadIdx.x;
    if (idx >= NB * NF) return;
    int b = idx / NF;
    nrm[idx] = energy[idx] / (med[b] + 1e-6f);
}

// Global quantile: 2-D distributed rank selection.
__global__ __launch_bounds__(256) void rankpart_kernel(const float* __restrict__ nrm,
                                                       int* __restrict__ rankpart) {
    const int n = NB * NF;
    int cb = blockIdx.x / 17;
    int chunk = blockIdx.x % 17;
    __shared__ __align__(16) float cdata[1024];
    int base = chunk * 1024;
    for (int t = threadIdx.x; t < 1024; t += 256)
        cdata[t] = (base + t < n) ? nrm[base + t] : INFINITY;
    __syncthreads();
    int i = cb * 256 + threadIdx.x;
    if (i >= n) return;
    float ei = nrm[i];
    int rank = 0;
#pragma unroll 8
    for (int t4 = 0; t4 < 256; ++t4) {
        float4 v = ((const float4*)cdata)[t4];
        int j = base + t4 * 4;
        rank += (v.x < ei) || (v.x == ei && j + 0 < i);
        rank += (v.y < ei) || (v.y == ei && j + 1 < i);
        rank += (v.z < ei) || (v.z == ei && j + 2 < i);
        rank += (v.w < ei) || (v.w == ei && j + 3 < i);
    }
    rankpart[(size_t)i * 17 + chunk] = rank;
}

__global__ __launch_bounds__(256) void rankreduce_kernel(const int* __restrict__ rankpart,
                                                         const float* __restrict__ nrm,
                                                         const float* __restrict__ q,
                                                         float* __restrict__ vk) {
    const int n = NB * NF;
    int i = blockIdx.x * 256 + threadIdx.x;
    if (i >= n) return;
    int rank = 0;
    const int* rp = rankpart + (size_t)i * 17;
#pragma unroll
    for (int c = 0; c < 17; ++c) rank += rp[c];
    double pos = (double)q[0] * (double)(n - 1);
    int k0 = (int)floor(pos);
    int k1 = min(k0 + 1, n - 1);
    if (rank == k0) vk[0] = nrm[i];
    if (rank == k1) vk[1] = nrm[i];
}

__global__ void thresh_kernel(const float* __restrict__ vk,
                              const float* __restrict__ q,
                              float* __restrict__ thr) {
    if (threadIdx.x == 0 && blockIdx.x == 0) {
        const int n = NB * NF;
        double pos = (double)q[0] * (double)(n - 1);
        double k0 = floor(pos);
        double frac = pos - k0;
        thr[0] = (float)((double)vk[0] + ((double)vk[1] - (double)vk[0]) * frac);
    }
}

// ---------------------------------------------------------------------------
// Scores via MFMA: async global_load_lds staging (XOR chunk swizzle, no pad),
// B2 derived in-register from B1, LDS-staged coalesced C-write.
// ---------------------------------------------------------------------------
__global__ __launch_bounds__(256, 2) void score_kernel(const bf16* __restrict__ Xb,
                                                       const bf16* __restrict__ K1,
                                                       bf16* __restrict__ S) {
    __shared__ __align__(16) char smem[34816];
    bf16* As  = (bf16*)smem;            // 128 rows x 64 bf16, chunks XOR-swizzled
    bf16* B1s = (bf16*)(smem + 16384);  // same layout
    int blk = blockIdx.x;
    int b = blk & 7;
    int t2 = blk >> 3;
    int f0 = (t2 / 17) * 128;
    int g0 = (t2 % 17) * 128;
    int tid = threadIdx.x;
    int wave = tid >> 6, lane = tid & 63;
    int m = lane & 15, quad = lane >> 4;
    int row_off = (wave & 1) * 64, col_off = (wave >> 1) * 64;

    f32x4 accRe[4][4] = {};
    f32x4 accIm[4][4] = {};
    const bf16* Abase = Xb + ((size_t)b * FP + f0) * 256;
    const bf16* Kbase = K1 + ((size_t)b * FP + g0) * 256;
    int lrow = lane >> 3;            // row within 8-row group
    int cswz = (lane & 7) ^ lrow;    // fetch chunk = position ^ (row&7)
    int mk = m & 7;

    for (int kk = 0; kk < 256; kk += 64) {
        __syncthreads();
#pragma unroll
        for (int t = 0; t < 4; ++t) {
            int r0 = wave * 32 + t * 8;   // wave-uniform
            async16(Abase + (size_t)(r0 + lrow) * 256 + kk + cswz * 8, As + r0 * 64);
            async16(Kbase + (size_t)(r0 + lrow) * 256 + kk + cswz * 8, B1s + r0 * 64);
        }
        __syncthreads();
#pragma unroll
        for (int k2 = 0; k2 < 64; k2 += 32) {
            bf16x8 a[4], b1[4], b2[4];
            int cb = k2 >> 3;
            int pos = ((cb + quad) ^ mk) << 3;
#pragma unroll
            for (int i = 0; i < 4; ++i)
                a[i] = *(const bf16x8*)&As[(row_off + i * 16 + m) * 64 + pos];
#pragma unroll
            for (int j = 0; j < 4; ++j) {
                b1[j] = *(const bf16x8*)&B1s[(col_off + j * 16 + m) * 64 + pos];
                b2[j] = derive_b2(b1[j]);
            }
#pragma unroll
            for (int i = 0; i < 4; ++i)
#pragma unroll
                for (int j = 0; j < 4; ++j) {
                    accRe[i][j] = __builtin_amdgcn_mfma_f32_16x16x32_bf16(a[i], b1[j], accRe[i][j], 0, 0, 0);
                    accIm[i][j] = __builtin_amdgcn_mfma_f32_16x16x32_bf16(a[i], b2[j], accIm[i][j], 0, 0, 0);
                }
        }
    }
    const float SCALE = 0.08838834764831845f;  // 1/sqrt(128)
    __syncthreads();
    bf16 (*Cs)[136] = (bf16(*)[136])smem;  // 128 x 136 bf16 = 34816 B
#pragma unroll
    for (int i = 0; i < 4; ++i)
#pragma unroll
        for (int j = 0; j < 4; ++j)
#pragma unroll
            for (int r = 0; r < 4; ++r) {
                float re = accRe[i][j][r], im = accIm[i][j][r];
                Cs[row_off + i * 16 + quad * 4 + r][col_off + j * 16 + m] =
                    (bf16)(sqrtf(re * re + im * im) * SCALE);
            }
    __syncthreads();
    bf16* Sb = S + (size_t)b * FP * FP;
    int row = tid >> 1, half = tid & 1;
    const bf16* src = &Cs[row][half * 64];
    bf16* dst = Sb + (size_t)(f0 + row) * FP + g0 + half * 64;
#pragma unroll
    for (int u = 0; u < 8; ++u)
        *(bf16x8*)&dst[u * 8] = *(const bf16x8*)&src[u * 8];
}

// single-read row softmax in place (bf16), zero pad cols
__global__ __launch_bounds__(256) void softmax_kernel(bf16* __restrict__ S) {
    int bf = blockIdx.x;
    int b = bf / NF, f = bf % NF;
    bf16* row = S + ((size_t)b * FP + f) * FP;
    int t = threadIdx.x;
    __shared__ float red[256];
    bf16x8 raw = *(const bf16x8*)&row[t * 8];  // covers g = 0..2047
    float tail = (t == 0) ? (float)row[2048] : -1e30f;
    float v[8];
    float mx = tail;
#pragma unroll
    for (int u = 0; u < 8; ++u) { v[u] = (float)raw[u]; mx = fmaxf(mx, v[u]); }
    red[t] = mx;
    __syncthreads();
    for (int s = 128; s > 0; s >>= 1) {
        if (t < s) red[t] = fmaxf(red[t], red[t + s]);
        __syncthreads();
    }
    float mval = red[0];
    __syncthreads();
    float sum = 0.f;
#pragma unroll
    for (int u = 0; u < 8; ++u) { v[u] = __expf(v[u] - mval); sum += v[u]; }
    float tex = 0.f;
    if (t == 0) { tex = __expf(tail - mval); sum += tex; }
    red[t] = sum;
    __syncthreads();
    for (int s = 128; s > 0; s >>= 1) {
        if (t < s) red[t] += red[t + s];
        __syncthreads();
    }
    float inv = 1.f / red[0];
    bf16x8 outv;
#pragma unroll
    for (int u = 0; u < 8; ++u) outv[u] = (bf16)(v[u] * inv);
    *(bf16x8*)&row[t * 8] = outv;
    if (t == 0) row[2048] = (bf16)(tex * inv);
    if (t < FP - NF) row[NF + t] = (bf16)0.f;
}

// ---------------------------------------------------------------------------
// Context via MFMA: Ctx[f,j] = sum_g P[f,g] Vt[j,g]. XCD-swizzled.
// ---------------------------------------------------------------------------
__global__ __launch_bounds__(256, 2) void context_kernel(const bf16* __restrict__ P,
                                                         const bf16* __restrict__ Vt,
                                                         float* __restrict__ Ctx) {
    __shared__ bf16 Ps[64][LDP];
    __shared__ bf16 Vs[256][LDP];
    int blk = blockIdx.x;
    int b = blk & 7;
    int f0 = (blk >> 3) * 64;
    int tid = threadIdx.x;
    int wave = tid >> 6, lane = tid & 63;
    int m = lane & 15, quad = lane >> 4;
    int col_off = wave * 64;

    f32x4 acc[4][4] = {};
    const bf16* Pbase = P + ((size_t)b * FP + f0) * FP;
    const bf16* Vbase = Vt + (size_t)b * 256 * FP;
    int r0 = tid >> 3, c0 = (tid & 7) * 8;

    for (int kk = 0; kk < FP; kk += 64) {
        __syncthreads();
#pragma unroll
        for (int s = 0; s < 2; ++s) {
            int r = r0 + 32 * s;
            *(bf16x8*)&Ps[r][c0] = *(const bf16x8*)&Pbase[(size_t)r * FP + kk + c0];
        }
#pragma unroll
        for (int s = 0; s < 8; ++s) {
            int r = r0 + 32 * s;
            *(bf16x8*)&Vs[r][c0] = *(const bf16x8*)&Vbase[(size_t)r * FP + kk + c0];
        }
        __syncthreads();
#pragma unroll
        for (int k2 = 0; k2 < 64; k2 += 32) {
            bf16x8 a[4], bb[4];
            int kq = k2 + quad * 8;
#pragma unroll
            for (int i = 0; i < 4; ++i) a[i] = *(const bf16x8*)&Ps[i * 16 + m][kq];
#pragma unroll
            for (int j = 0; j < 4; ++j) bb[j] = *(const bf16x8*)&Vs[col_off + j * 16 + m][kq];
#pragma unroll
            for (int i = 0; i < 4; ++i)
#pragma unroll
                for (int j = 0; j < 4; ++j)
                    acc[i][j] = __builtin_amdgcn_mfma_f32_16x16x32_bf16(a[i], bb[j], acc[i][j], 0, 0, 0);
        }
    }
#pragma unroll
    for (int i = 0; i < 4; ++i)
#pragma unroll
        for (int j = 0; j < 4; ++j)
#pragma unroll
            for (int r = 0; r < 4; ++r) {
                int row = f0 + i * 16 + quad * 4 + r;
                int col = col_off + j * 16 + m;
                if (row < NF) Ctx[((size_t)b * NF + row) * 256 + col] = acc[i][j][r];
            }
}

// Fused hifreq + transpose: Ctxt[b, ch, f] = Ctx[b,f,ch] + mask*(X*w_hi)
__global__ __launch_bounds__(256) void ctxt_kernel(const float2* __restrict__ Ctx2,
                                                   const float2* __restrict__ Xf2,
                                                   const float* __restrict__ nrm,
                                                   const float* __restrict__ thr,
                                                   const float* __restrict__ w_high,
                                                   float* __restrict__ Ctxt) {
    __shared__ float2 tile[64][33];
    int blk = blockIdx.x;
    int b = blk / 132;
    int t2 = blk % 132;
    int cp0 = (t2 / 33) * 32;
    int f0 = (t2 % 33) * 64;
    int t = threadIdx.x;
    float thrv = thr[0];
    int cpl = t & 31, rr = t >> 5;
#pragma unroll
    for (int rb = 0; rb < 8; ++rb) {
        int fl = rb * 8 + rr;
        int f = f0 + fl;
        float2 v = make_float2(0.f, 0.f);
        if (f < NF) {
            size_t idx = ((size_t)b * NF + f) * 128 + cp0 + cpl;
            v = Ctx2[idx];
            if (nrm[b * NF + f] > thrv) {
                float2 x = Xf2[idx];
                int c = cp0 + cpl;
                float wr = w_high[2 * c], wi = w_high[2 * c + 1];
                v.x += x.x * wr - x.y * wi;
                v.y += x.x * wi + x.y * wr;
            }
        }
        tile[fl][cpl] = v;
    }
    __syncthreads();
    int fl = t & 63, ww = t >> 6;
#pragma unroll
    for (int wb = 0; wb < 16; ++wb) {
        int chl = wb * 4 + ww;
        int f = f0 + fl;
        if (f < NF) {
            float2 v = tile[fl][chl >> 1];
            Ctxt[((size_t)b * 256 + 2 * cp0 + chl) * NF + f] = (chl & 1) ? v.y : v.x;
        }
    }
}

// irfft (ortho) reading contiguous Ctxt rows
__global__ __launch_bounds__(256) void fft_inv_kernel(const float* __restrict__ Ctxt,
                                                      float* __restrict__ out) {
    __shared__ float2 buf[NT];
    int bc = blockIdx.x, b = bc >> 7, c = bc & 127;
    const float* base = Ctxt + ((size_t)b * 256 + 2 * c) * NF;
    const float* basei = base + NF;
    for (int f = threadIdx.x; f < NT; f += 256) {
        float re, im;
        if (f <= NT / 2) {
            re = base[f];
            im = -basei[f];
        } else {
            int g = NT - f;
            re = base[g];
            im = basei[g];
        }
        int r = __brev((unsigned)f) >> 20;
        buf[r] = make_float2(re, im);
    }
    fft4096(buf);
    float* orow = out + (size_t)bc * NT;
    const float inv = 1.0f / 64.0f;
    for (int n = threadIdx.x; n < NT; n += 256) orow[n] = buf[n].x * inv;
}

extern "C" void kernel_launch(void* const* d_in, const int* in_sizes, int n_in,
                              void* d_out, int out_size, void* d_ws, size_t ws_size,
                              hipStream_t stream) {
    const float* x_in = (const float*)d_in[0];
    const float* W_K = (const float*)d_in[1];
    const float* b_K = (const float*)d_in[2];
    const float* W_V = (const float*)d_in[3];
    const float* b_V = (const float*)d_in[4];
    const float* w_high = (const float*)d_in[5];
    const float* qpar = (const float*)d_in[6];
    float* out = (float*)d_out;

    char* w = (char*)d_ws;
    const size_t SPECB = (size_t)NB * NF * 256 * 4;       // 16.8 MB
    float* Xf = (float*)w;            w += SPECB;
    float* Ctx = (float*)w;           w += SPECB;
    float* energy = (float*)w;        w += (size_t)NB * NF * 4;
    float* med = (float*)w;           w += 64;
    float* nrm = (float*)w;           w += (size_t)NB * NF * 4;
    float* vk = (float*)w;            w += 64;
    float* thr = (float*)w;           w += 64;
    w = (char*)(((uintptr_t)w + 255) & ~(uintptr_t)255);
    int* rankpart = (int*)w;          w += (size_t)16640 * 17 * 4;      // 1.1 MB
    w = (char*)(((uintptr_t)w + 255) & ~(uintptr_t)255);
    bf16* S = (bf16*)w;               w += (size_t)NB * FP * FP * 2;    // 75.8 MB
    bf16* Xb = (bf16*)w;              w += (size_t)NB * FP * 256 * 2;   // 8.9 MB
    bf16* K1 = (bf16*)w;              w += (size_t)NB * FP * 256 * 2;   // 8.9 MB
    bf16* Vt = (bf16*)w;              w += (size_t)NB * 256 * FP * 2;   // 8.9 MB
    bf16* Wk1 = (bf16*)w;             w += (size_t)256 * 256 * 2;
    bf16* Av = (bf16*)w;              w += (size_t)256 * 256 * 2;
    // Aliases (lifetimes disjoint):
    float2* Xc = (float2*)S;      // used only fft_fwd -> xt (S written later)
    float* Ctxt = (float*)Xb;     // 16.8 MB over Xb+K1 (both dead after score)

    fft_fwd_kernel<<<NB * NC, 256, 0, stream>>>(x_in, Xc);
    xt_kernel<<<NB * 2 * 34, 256, 0, stream>>>(Xc, (float2*)Xf, Xb);
    wpack_kernel<<<256, 256, 0, stream>>>(W_K, W_V, Wk1, Av);
    kvgemm_kernel<<<NB * 17 * 2, 256, 0, stream>>>(Xb, Wk1, K1);
    vtgemm_kernel<<<NB * 17 * 2, 256, 0, stream>>>(Av, Xb, Vt);
    biasfix_kernel<<<NB, 128, 0, stream>>>(b_K, b_V, K1, Vt);
    energy_kernel<<<(NB * NF + 255) / 256, 256, 0, stream>>>(Xf, energy);
    median_kernel<<<NB * 9, 256, 0, stream>>>(energy, med);
    norm_kernel<<<(NB * NF + 255) / 256, 256, 0, stream>>>(energy, med, nrm);
    rankpart_kernel<<<65 * 17, 256, 0, stream>>>(nrm, rankpart);
    rankreduce_kernel<<<65, 256, 0, stream>>>(rankpart, nrm, qpar, vk);
    thresh_kernel<<<1, 64, 0, stream>>>(vk, qpar, thr);
    score_kernel<<<NB * 17 * 17, 256, 0, stream>>>(Xb, K1, S);
    softmax_kernel<<<NB * NF, 256, 0, stream>>>(S);
    context_kernel<<<NB * 33, 256, 0, stream>>>(S, Vt, Ctx);
    ctxt_kernel<<<NB * 4 * 33, 256, 0, stream>>>((const float2*)Ctx, (const float2*)Xf,
                                                 nrm, thr, w_high, Ctxt);
    fft_inv_kernel<<<NB * NC, 256, 0, stream>>>(Ctxt, out);
}